// Round 1
// baseline (2760.412 us; speedup 1.0000x reference)
//
#include <hip/hip_runtime.h>

// ---------------------------------------------------------------------------
// EPROP3_LSTM: e-prop LSTM fwd.  Reformulation:
//   ev_x[b,j,k] = sum_t A_t[b,j] * x_t[b,k],   A_t = d_t * F_t, F_t = prod_{s>t} f_s
//   ev_h[b,j,k] = sum_t A_t[b,j] * h_{t-1}[b,k]
//   ev_b[b,j]   = sum_t A_t[b,j]
// => sequential LSTM recurrence + suffix scan + batched GEMMs (K=T=128).
// ---------------------------------------------------------------------------

typedef __attribute__((ext_vector_type(8))) short short8;
typedef __attribute__((ext_vector_type(4))) float f32x4;

#define DEV static __device__ __forceinline__

DEV unsigned short f2bf(float x) {
  union { float f; unsigned u; } v; v.f = x;
  return (unsigned short)((v.u + 0x7fffu + ((v.u >> 16) & 1u)) >> 16);
}
DEV float bf2f(unsigned short b) {
  union { float f; unsigned u; } v; v.u = ((unsigned)b) << 16;
  return v.f;
}

// ---------------------------------------------------------------------------
// Persistent LSTM recurrence.  64 WGs x 256 threads.  WG wg owns hidden units
// jh in [wg*8, wg*8+8)  -> 32 gate rows (4 gates x 8).  Whh slice held in
// registers as bf16 hi/lo MFMA B-fragments (3-term split ~= fp32 accuracy).
// Per step: gates[32b x 32r] = XW + H[t] @ Whh_slice^T via mfma 16x16x32 bf16,
// elementwise LSTM update, write H[t+1]/d/f, then device-scope barrier.
// ---------------------------------------------------------------------------
__global__ __launch_bounds__(256, 1) void lstm_rec(
    const float* __restrict__ Whh,        // [2048][512]
    const float* __restrict__ XW,         // [128][32][2048]  x@Wih^T + b
    unsigned short* __restrict__ Hhi,     // [129][32][512] bf16 hi
    unsigned short* __restrict__ Hlo,     // [129][32][512] bf16 lo
    float* __restrict__ Hf,               // [129][32][512] fp32
    float* __restrict__ dh,               // [128][32][1536]
    float* __restrict__ fh,               // [128][32][512]
    int* __restrict__ cnt)                // [128] barrier counters (pre-zeroed)
{
  const int wg   = blockIdx.x;            // 0..63
  const int tid  = threadIdx.x;           // 0..255
  const int lane = tid & 63;
  const int wave = tid >> 6;
  const int tM   = wave & 1;              // batch-tile
  const int tN   = wave >> 1;             // row-tile

  __shared__ float gl[32][36];            // gates tile [b][r], padded

  // ---- load Whh B-fragments once (hi/lo bf16 split) ----
  // B[k][n] layout: lane holds B[32s + 8*(lane>>4) + j][lane&15]
  const int cc   = lane & 15;
  const int kb   = lane >> 4;
  const int rloc = tN * 16 + cc;                          // local row 0..31
  const int jglob = (rloc >> 3) * 512 + wg * 8 + (rloc & 7); // global gate row
  short8 whi[16], wlo[16];
#pragma unroll
  for (int s = 0; s < 16; ++s) {
    const float* wp = Whh + (size_t)jglob * 512 + s * 32 + kb * 8;
    f32x4 w0 = *(const f32x4*)wp;
    f32x4 w1 = *(const f32x4*)(wp + 4);
    short8 hi, lo;
#pragma unroll
    for (int j = 0; j < 4; ++j) {
      unsigned short h0 = f2bf(w0[j]);
      hi[j] = (short)h0;  lo[j] = (short)f2bf(w0[j] - bf2f(h0));
      unsigned short h1 = f2bf(w1[j]);
      hi[4 + j] = (short)h1;  lo[4 + j] = (short)f2bf(w1[j] - bf2f(h1));
    }
    whi[s] = hi; wlo[s] = lo;
  }

  const int bA  = tM * 16 + cc;     // A-fragment batch row
  const int kA0 = kb * 8;           // A-fragment k offset within K-step
  const int be  = tid >> 3;         // elementwise: batch
  const int jo  = tid & 7;          // elementwise: local hidden unit
  const int jh  = wg * 8 + jo;      // global hidden unit
  float c_reg = 0.f;

  for (int t = 0; t < 128; ++t) {
    // ---- MFMA: gates_tile = H[t] @ Whh_slice^T  (hi/lo 3-term split) ----
    f32x4 acc = {0.f, 0.f, 0.f, 0.f};
    const unsigned short* ph = Hhi + (size_t)t * 16384 + (size_t)bA * 512 + kA0;
    const unsigned short* pl = Hlo + (size_t)t * 16384 + (size_t)bA * 512 + kA0;
#pragma unroll
    for (int s = 0; s < 16; ++s) {
      short8 ah = *(const short8*)(ph + s * 32);
      short8 al = *(const short8*)(pl + s * 32);
      acc = __builtin_amdgcn_mfma_f32_16x16x32_bf16(ah, whi[s], acc, 0, 0, 0);
      acc = __builtin_amdgcn_mfma_f32_16x16x32_bf16(ah, wlo[s], acc, 0, 0, 0);
      acc = __builtin_amdgcn_mfma_f32_16x16x32_bf16(al, whi[s], acc, 0, 0, 0);
    }
    // D layout: row m = 16*tM + 4*(lane>>4)+reg (batch), col n = 16*tN + (lane&15)
#pragma unroll
    for (int r = 0; r < 4; ++r)
      gl[tM * 16 + kb * 4 + r][tN * 16 + cc] = acc[r];
    __syncthreads();

    // ---- elementwise LSTM update: thread = (batch be, unit jo) ----
    {
      const float* xwp = XW + (size_t)t * 65536 + (size_t)be * 2048 + wg * 8 + jo;
      float pi = xwp[0]    + gl[be][jo];
      float pf = xwp[512]  + gl[be][8  + jo];
      float pg = xwp[1024] + gl[be][16 + jo];
      float po = xwp[1536] + gl[be][24 + jo];
      float ig = 1.f / (1.f + expf(-pi));
      float fg = 1.f / (1.f + expf(-pf));
      float gg = tanhf(pg);
      float og = 1.f / (1.f + expf(-po));
      float di = gg * ig * (1.f - ig);
      float df = c_reg * fg * (1.f - fg);     // uses c_{t-1}
      float dg = ig * (1.f - gg * gg);
      c_reg = fg * c_reg + ig * gg;
      float hn = og * tanhf(c_reg);
      size_t ho = (size_t)(t + 1) * 16384 + (size_t)be * 512 + jh;
      unsigned short hh = f2bf(hn);
      Hf[ho]  = hn;
      Hhi[ho] = hh;
      Hlo[ho] = f2bf(hn - bf2f(hh));
      size_t db = (size_t)t * 49152 + (size_t)be * 1536 + jh;
      dh[db] = di; dh[db + 512] = df; dh[db + 1024] = dg;
      fh[(size_t)t * 16384 + (size_t)be * 512 + jh] = fg;
    }

    // ---- device-scope barrier across 64 WGs ----
    __threadfence();
    __syncthreads();
    if (tid == 0) {
      __hip_atomic_fetch_add(&cnt[t], 1, __ATOMIC_RELAXED, __HIP_MEMORY_SCOPE_AGENT);
      while (__hip_atomic_load(&cnt[t], __ATOMIC_RELAXED, __HIP_MEMORY_SCOPE_AGENT) < 64) {
        __builtin_amdgcn_s_sleep(2);
      }
    }
    __syncthreads();
    __threadfence();
  }
}

// ---------------------------------------------------------------------------
// Suffix scan: A_t = d_t * F_t (in place over dh), ev_b = sum_t A_t.
// One thread per (b, jh).
// ---------------------------------------------------------------------------
__global__ __launch_bounds__(256) void suffix_A(
    float* __restrict__ dh, const float* __restrict__ fh,
    float* __restrict__ evb)
{
  const int g = blockIdx.x * 256 + threadIdx.x;   // 0..16383
  const int b = g >> 9, jh = g & 511;
  float F = 1.f, s0 = 0.f, s1 = 0.f, s2 = 0.f;
  for (int t = 127; t >= 0; --t) {
    size_t db = (size_t)t * 49152 + (size_t)b * 1536 + jh;
    float a0 = dh[db] * F, a1 = dh[db + 512] * F, a2 = dh[db + 1024] * F;
    dh[db] = a0; dh[db + 512] = a1; dh[db + 1024] = a2;
    s0 += a0; s1 += a1; s2 += a2;
    F *= fh[(size_t)t * 16384 + (size_t)b * 512 + jh];
  }
  size_t eb = (size_t)b * 1536 + jh;
  evb[eb] = s0; evb[eb + 512] = s1; evb[eb + 1024] = s2;
}

// ---------------------------------------------------------------------------
// Generic strided batched fp32 GEMM: C[m][n] = sum_k A[.]*B[.] (+bias, relu).
// A addr: z*aBatch + m*sAm + k*sAk;  B addr: z*bBatch + n*sBn + k*sBk
// C addr: z*cBatch + (m%M1)*sCm1 + (m/M1)*sCm2 + n
// ---------------------------------------------------------------------------
template <int BM, int BN, int TM, int TN>
__global__ __launch_bounds__(256) void gemm_f32(
    const float* __restrict__ A, const float* __restrict__ B,
    float* __restrict__ C, const float* __restrict__ bias,
    int M, int N, int K,
    long long sAm, long long sAk, long long aBatch,
    long long sBn, long long sBk, long long bBatch,
    long long sCm1, long long sCm2, int M1, long long cBatch,
    int relu)
{
  constexpr int BK = 16;
  __shared__ float As[BK][BM + 4];
  __shared__ float Bs[BK][BN + 4];
  const int tid = threadIdx.x;
  const long long z = blockIdx.z;
  const float* Ab = A + z * aBatch;
  const float* Bb = B + z * bBatch;
  const int m0 = blockIdx.y * BM, n0 = blockIdx.x * BN;
  constexpr int tn_cnt = BN / TN;
  const int tm0 = (tid / tn_cnt) * TM;
  const int tn0 = (tid % tn_cnt) * TN;

  float acc[TM][TN];
#pragma unroll
  for (int i = 0; i < TM; ++i)
#pragma unroll
    for (int j = 0; j < TN; ++j) acc[i][j] = 0.f;

  for (int k0 = 0; k0 < K; k0 += BK) {
    // ---- stage A ----
    if (sAk == 1) {
      for (int m = tid >> 2; m < BM; m += 64) {
        const int kq = (tid & 3) * 4;
        f32x4 v = {0.f, 0.f, 0.f, 0.f};
        if (m0 + m < M) v = *(const f32x4*)(Ab + (long long)(m0 + m) * sAm + (k0 + kq));
        As[kq + 0][m] = v[0]; As[kq + 1][m] = v[1];
        As[kq + 2][m] = v[2]; As[kq + 3][m] = v[3];
      }
    } else {  // sAm == 1
      constexpr int mq_cnt = BM / 4;
      for (int kk = tid / mq_cnt; kk < BK; kk += 256 / mq_cnt) {
        const int mq = (tid % mq_cnt) * 4;
        f32x4 v = {0.f, 0.f, 0.f, 0.f};
        if (m0 + mq < M) v = *(const f32x4*)(Ab + (long long)(k0 + kk) * sAk + (m0 + mq));
        *(f32x4*)&As[kk][mq] = v;
      }
    }
    // ---- stage B ----
    if (sBk == 1) {
      for (int n = tid >> 2; n < BN; n += 64) {
        const int kq = (tid & 3) * 4;
        f32x4 v = {0.f, 0.f, 0.f, 0.f};
        if (n0 + n < N) v = *(const f32x4*)(Bb + (long long)(n0 + n) * sBn + (k0 + kq));
        Bs[kq + 0][n] = v[0]; Bs[kq + 1][n] = v[1];
        Bs[kq + 2][n] = v[2]; Bs[kq + 3][n] = v[3];
      }
    } else {  // sBn == 1
      constexpr int nq_cnt = BN / 4;
      for (int kk = tid / nq_cnt; kk < BK; kk += 256 / nq_cnt) {
        const int nq = (tid % nq_cnt) * 4;
        f32x4 v = {0.f, 0.f, 0.f, 0.f};
        if (n0 + nq < N) v = *(const f32x4*)(Bb + (long long)(k0 + kk) * sBk + (n0 + nq));
        *(f32x4*)&Bs[kk][nq] = v;
      }
    }
    __syncthreads();

#pragma unroll
    for (int kk = 0; kk < BK; ++kk) {
      float a[TM], bb[TN];
      if constexpr (TM == 8) {
        f32x4 a0 = *(const f32x4*)&As[kk][tm0];
        f32x4 a1 = *(const f32x4*)&As[kk][tm0 + 4];
#pragma unroll
        for (int i = 0; i < 4; ++i) { a[i] = a0[i]; a[4 + i] = a1[i]; }
      } else {
#pragma unroll
        for (int i = 0; i < TM; ++i) a[i] = As[kk][tm0 + i];
      }
      if constexpr (TN == 8) {
        f32x4 b0 = *(const f32x4*)&Bs[kk][tn0];
        f32x4 b1 = *(const f32x4*)&Bs[kk][tn0 + 4];
#pragma unroll
        for (int j = 0; j < 4; ++j) { bb[j] = b0[j]; bb[4 + j] = b1[j]; }
      } else {
#pragma unroll
        for (int j = 0; j < TN; ++j) bb[j] = Bs[kk][tn0 + j];
      }
#pragma unroll
      for (int i = 0; i < TM; ++i)
#pragma unroll
        for (int j = 0; j < TN; ++j) acc[i][j] += a[i] * bb[j];
    }
    __syncthreads();
  }

  // ---- epilogue ----
#pragma unroll
  for (int i = 0; i < TM; ++i) {
    const int mg = m0 + tm0 + i;
    if (mg >= M) continue;
    const long long crow = z * cBatch + (long long)(mg % M1) * sCm1 +
                           (long long)(mg / M1) * sCm2;
#pragma unroll
    for (int j = 0; j < TN; ++j) {
      const int ng = n0 + tn0 + j;
      if (ng >= N) continue;
      float v = acc[i][j];
      if (bias) v += bias[ng];
      if (relu) v = fmaxf(v, 0.f);
      C[crow + ng] = v;
    }
  }
}

// ---------------------------------------------------------------------------
extern "C" void kernel_launch(void* const* d_in, const int* in_sizes, int n_in,
                              void* d_out, int out_size, void* d_ws, size_t ws_size,
                              hipStream_t stream) {
  const float* x   = (const float*)d_in[0];
  const float* Wih = (const float*)d_in[1];
  const float* Whh = (const float*)d_in[2];
  const float* bl  = (const float*)d_in[3];
  const float* Wd  = (const float*)d_in[4];
  const float* bd  = (const float*)d_in[5];
  const float* Ws1 = (const float*)d_in[6];
  const float* bs1 = (const float*)d_in[7];
  const float* Ws2 = (const float*)d_in[8];
  const float* bs2 = (const float*)d_in[9];
  const float* Ws3 = (const float*)d_in[10];
  const float* bs3 = (const float*)d_in[11];
  const float* Ws4 = (const float*)d_in[12];
  const float* bs4 = (const float*)d_in[13];

  float* out = (float*)d_out;
  float* ws  = (float*)d_ws;

  // d_out layout (floats)
  const long long OP = 0, OS = 320, OEX = 16704, OEH = 12599616, OEB = 37765440;

  // scratch inside ev_h output region (dead before final ev_h GEMM writes it)
  float* XW = out + OEH;                              // [128][32][2048]
  float* fh = out + OEH + 8388608;                    // [128][32][512]
  unsigned short* Hhi = (unsigned short*)(out + OEH + 10485760); // [129][32][512]
  unsigned short* Hlo = Hhi + 2113536;

  // ws scratch (~33.7 MB)
  float* dh = ws;                       // [128][32][1536]  d -> A in place
  float* Hf = ws + 6291456;             // [129][32][512] fp32
  float* z1 = ws + 8404992;             // [32][512]
  float* z2 = ws + 8421376;             // [32][256]
  float* z3 = ws + 8429568;             // [32][128]
  int*  cnt = (int*)(ws + 8433664);     // [128]

  hipMemsetAsync(cnt, 0, 128 * sizeof(int), stream);
  hipMemsetAsync(Hf,  0, 16384 * sizeof(float), stream);          // H[0] = 0
  hipMemsetAsync(Hhi, 0, 16384 * sizeof(unsigned short), stream);
  hipMemsetAsync(Hlo, 0, 16384 * sizeof(unsigned short), stream);

  dim3 blk(256);

  // K1: XW[t][b][j] = x @ Wih^T + b_lstm   (M=4096 (b,t), N=2048, K=256)
  gemm_f32<128, 128, 8, 8><<<dim3(16, 32, 1), blk, 0, stream>>>(
      x, Wih, XW, bl, 4096, 2048, 256,
      256, 1, 0,            // A: x[m][k]
      256, 1, 0,            // B: Wih[n][k]
      65536, 2048, 128, 0,  // C: XW[t= m%128][b= m/128][n]
      0);

  // K2: persistent recurrence
  lstm_rec<<<dim3(64), blk, 0, stream>>>(Whh, XW, Hhi, Hlo, Hf, dh, fh, cnt);

  // K3: suffix products, A in place, ev_b
  suffix_A<<<dim3(64), blk, 0, stream>>>(dh, fh, out + OEB);

  // MLP + readout on last = Hf[128]
  const float* hlast = Hf + 2097152;
  gemm_f32<32, 32, 2, 2><<<dim3(16, 1, 1), blk, 0, stream>>>(
      hlast, Ws1, z1, bs1, 32, 512, 512, 512, 1, 0, 512, 1, 0, 512, 0, 32, 0, 1);
  gemm_f32<32, 32, 2, 2><<<dim3(8, 1, 1), blk, 0, stream>>>(
      z1, Ws2, z2, bs2, 32, 256, 512, 512, 1, 0, 512, 1, 0, 256, 0, 32, 0, 1);
  gemm_f32<32, 32, 2, 2><<<dim3(4, 1, 1), blk, 0, stream>>>(
      z2, Ws3, z3, bs3, 32, 128, 256, 256, 1, 0, 256, 1, 0, 128, 0, 32, 0, 1);
  gemm_f32<32, 32, 2, 2><<<dim3(16, 1, 1), blk, 0, stream>>>(
      z3, Ws4, out + OS, bs4, 32, 512, 128, 128, 1, 0, 128, 1, 0, 512, 0, 32, 0, 0);
  gemm_f32<32, 32, 2, 2><<<dim3(1, 1, 1), blk, 0, stream>>>(
      hlast, Wd, out + OP, bd, 32, 10, 512, 512, 1, 0, 512, 1, 0, 10, 0, 32, 0, 0);

  // K4: ev_x[b][j][i] = sum_t A[t][b][j] * x[b][t][i]  (M=1536, N=256, K=128)
  gemm_f32<128, 128, 8, 8><<<dim3(2, 12, 32), blk, 0, stream>>>(
      dh, x, out + OEX, nullptr, 1536, 256, 128,
      1, 49152, 1536,       // A: dh[t][b][j], m=j contiguous
      1, 256, 32768,        // B: x[b][t][i], n=i contiguous
      256, 0, 1536, 393216,
      0);

  // K5: ev_h[b][j][k] = sum_t A[t][b][j] * h_{t-1}[b][k]  (M=1536, N=512, K=128)
  // (runs last: overwrites XW/fh/Hhi/Hlo scratch living in the ev_h region)
  gemm_f32<128, 128, 8, 8><<<dim3(4, 12, 32), blk, 0, stream>>>(
      dh, Hf, out + OEH, nullptr, 1536, 512, 128,
      1, 49152, 1536,       // A: dh[t][b][j]
      1, 16384, 512,        // B: Hf[t][b][k], n=k contiguous
      512, 0, 1536, 786432,
      0);
}

// Round 2
// 1009.168 us; speedup vs baseline: 2.7353x; 2.7353x over previous
//
#include <hip/hip_runtime.h>

// ---------------------------------------------------------------------------
// EPROP3_LSTM: e-prop LSTM fwd.  Reformulation:
//   ev_x[b,j,k] = sum_t A_t[b,j] * x_t[b,k],   A_t = d_t * F_t, F_t = prod_{s>t} f_s
//   ev_h[b,j,k] = sum_t A_t[b,j] * h_{t-1}[b,k]
//   ev_b[b,j]   = sum_t A_t[b,j]
// => sequential LSTM recurrence + suffix scan + batched GEMMs (K=T=128).
//
// Recurrence sync design (round 2): NO __threadfence (agent fences flush the
// per-XCD L2 every step -> 18.7us/step).  Only the h-exchange array Hp is
// device-coherent, via sc1 ops: __hip_atomic_store/load(RELAXED, AGENT).
// Barrier: s_waitcnt vmcnt(0) + relaxed agent atomics on 8 spread counters.
// ---------------------------------------------------------------------------

typedef __attribute__((ext_vector_type(8))) short short8;
typedef __attribute__((ext_vector_type(4))) float f32x4;
typedef __attribute__((ext_vector_type(4))) unsigned u32x4;
typedef __attribute__((ext_vector_type(4))) int i32x4;

#define DEV static __device__ __forceinline__

DEV unsigned short f2bf(float x) {
  union { float f; unsigned u; } v; v.f = x;
  return (unsigned short)((v.u + 0x7fffu + ((v.u >> 16) & 1u)) >> 16);
}
DEV float bf2f(unsigned short b) {
  union { float f; unsigned u; } v; v.u = ((unsigned)b) << 16;
  return v.f;
}

// ---------------------------------------------------------------------------
// Persistent LSTM recurrence.  32 WGs x 512 threads.  WG wg owns hidden units
// jh in [wg*16, wg*16+16) -> 64 gate rows (4 gates x 16).  Whh slice held in
// registers as bf16 hi/lo MFMA B-fragments (3-term split ~= fp32 accuracy).
// Per step: stage packed h-tile (sc1 loads) into LDS, gates = XW + H @ Whh^T
// via mfma 16x16x32 bf16, elementwise LSTM update, sc1-store h, barrier.
// ---------------------------------------------------------------------------
__global__ __launch_bounds__(512, 2) void lstm_rec(
    const float* __restrict__ Whh,        // [2048][512]
    const float* __restrict__ XW,         // [128][32][2048]  x@Wih^T + b
    unsigned* __restrict__ Hp,            // [129][32][512] packed (hi<<16)|lo
    float* __restrict__ Hf,               // [129][32][512] fp32 (private)
    float* __restrict__ dh,               // [128][32][1536] (private)
    float* __restrict__ fh,               // [128][32][512] (private)
    unsigned* __restrict__ cnt)           // [128][8] stride-32 u32, pre-zeroed
{
  const int wg   = blockIdx.x;            // 0..31
  const int tid  = threadIdx.x;           // 0..511
  const int lane = tid & 63;
  const int wave = tid >> 6;              // 0..7
  const int tM   = wave & 1;              // batch-tile (0..1)
  const int tN   = wave >> 1;             // row-tile   (0..3)

  __shared__ unsigned Ld[32][516];        // packed h tile [b][k], padded
  __shared__ float gl[32][68];            // gates tile [b][r], padded

  const int cc = lane & 15;
  const int kb = lane >> 4;

  // ---- load Whh B-fragments once (hi/lo bf16 split) ----
  const int rloc  = tN * 16 + cc;                              // local row 0..63
  const int jglob = (rloc >> 4) * 512 + wg * 16 + (rloc & 15); // global gate row
  short8 whi[16], wlo[16];
#pragma unroll
  for (int s = 0; s < 16; ++s) {
    const float* wp = Whh + (size_t)jglob * 512 + s * 32 + kb * 8;
    f32x4 w0 = *(const f32x4*)wp;
    f32x4 w1 = *(const f32x4*)(wp + 4);
    short8 hi, lo;
#pragma unroll
    for (int j = 0; j < 4; ++j) {
      unsigned short h0 = f2bf(w0[j]);
      hi[j] = (short)h0;  lo[j] = (short)f2bf(w0[j] - bf2f(h0));
      unsigned short h1 = f2bf(w1[j]);
      hi[4 + j] = (short)h1;  lo[4 + j] = (short)f2bf(w1[j] - bf2f(h1));
    }
    whi[s] = hi; wlo[s] = lo;
  }

  const int bA = tM * 16 + cc;      // A-fragment batch row
  const int be = tid >> 4;          // elementwise: batch 0..31
  const int jo = tid & 15;          // elementwise: local hidden unit 0..15
  const int jh = wg * 16 + jo;      // global hidden unit
  float c_reg = 0.f;

  for (int t = 0; t < 128; ++t) {
    // ---- stage Hp[t] (32x512 u32 = 64KB) into LDS via sc1 loads ----
    {
      unsigned* Hpt = Hp + (size_t)t * 16384;
      unsigned v[32];
#pragma unroll
      for (int c2 = 0; c2 < 32; ++c2)
        v[c2] = __hip_atomic_load(Hpt + c2 * 512 + tid,
                                  __ATOMIC_RELAXED, __HIP_MEMORY_SCOPE_AGENT);
#pragma unroll
      for (int c2 = 0; c2 < 32; ++c2)
        Ld[c2][tid] = v[c2];
    }
    __syncthreads();

    // ---- MFMA: gates_tile = H[t] @ Whh_slice^T (hi/lo 3-term split) ----
    f32x4 acc = {0.f, 0.f, 0.f, 0.f};
#pragma unroll
    for (int s = 0; s < 16; ++s) {
      const int k0 = s * 32 + kb * 8;
      u32x4 qa = *(const u32x4*)&Ld[bA][k0];
      u32x4 qb = *(const u32x4*)&Ld[bA][k0 + 4];
      i32x4 hw, lw;
      hw[0] = (int)((qa[0] >> 16) | (qa[1] & 0xffff0000u));
      hw[1] = (int)((qa[2] >> 16) | (qa[3] & 0xffff0000u));
      hw[2] = (int)((qb[0] >> 16) | (qb[1] & 0xffff0000u));
      hw[3] = (int)((qb[2] >> 16) | (qb[3] & 0xffff0000u));
      lw[0] = (int)((qa[0] & 0xffffu) | (qa[1] << 16));
      lw[1] = (int)((qa[2] & 0xffffu) | (qa[3] << 16));
      lw[2] = (int)((qb[0] & 0xffffu) | (qb[1] << 16));
      lw[3] = (int)((qb[2] & 0xffffu) | (qb[3] << 16));
      short8 ah = __builtin_bit_cast(short8, hw);
      short8 al = __builtin_bit_cast(short8, lw);
      acc = __builtin_amdgcn_mfma_f32_16x16x32_bf16(ah, whi[s], acc, 0, 0, 0);
      acc = __builtin_amdgcn_mfma_f32_16x16x32_bf16(ah, wlo[s], acc, 0, 0, 0);
      acc = __builtin_amdgcn_mfma_f32_16x16x32_bf16(al, whi[s], acc, 0, 0, 0);
    }
    // D layout: row m = 16*tM + 4*(lane>>4)+r (batch), col n = 16*tN + (lane&15)
#pragma unroll
    for (int r = 0; r < 4; ++r)
      gl[tM * 16 + kb * 4 + r][tN * 16 + cc] = acc[r];
    __syncthreads();

    // ---- elementwise LSTM update: thread = (batch be, unit jo) ----
    {
      const float* xwp = XW + (size_t)t * 65536 + (size_t)be * 2048 + wg * 16 + jo;
      float pi = xwp[0]    + gl[be][jo];
      float pf = xwp[512]  + gl[be][16 + jo];
      float pg = xwp[1024] + gl[be][32 + jo];
      float po = xwp[1536] + gl[be][48 + jo];
      float ig = 1.f / (1.f + expf(-pi));
      float fg = 1.f / (1.f + expf(-pf));
      float gg = tanhf(pg);
      float og = 1.f / (1.f + expf(-po));
      float di = gg * ig * (1.f - ig);
      float df = c_reg * fg * (1.f - fg);     // uses c_{t-1}
      float dg = ig * (1.f - gg * gg);
      c_reg = fg * c_reg + ig * gg;
      float hn = og * tanhf(c_reg);
      size_t ho = (size_t)(t + 1) * 16384 + (size_t)be * 512 + jh;
      Hf[ho] = hn;
      unsigned hh = f2bf(hn);
      unsigned hl = f2bf(hn - bf2f((unsigned short)hh));
      __hip_atomic_store(&Hp[ho], (hh << 16) | hl,
                         __ATOMIC_RELAXED, __HIP_MEMORY_SCOPE_AGENT);
      size_t db = (size_t)t * 49152 + (size_t)be * 1536 + jh;
      dh[db] = di; dh[db + 512] = df; dh[db + 1024] = dg;
      fh[(size_t)t * 16384 + (size_t)be * 512 + jh] = fg;
    }

    // ---- device barrier across 32 WGs (no cache flushes) ----
    asm volatile("s_waitcnt vmcnt(0)" ::: "memory");  // drain sc1 h-stores
    __syncthreads();
    if (tid == 0)
      __hip_atomic_fetch_add(&cnt[t * 256 + (wg & 7) * 32], 1u,
                             __ATOMIC_RELAXED, __HIP_MEMORY_SCOPE_AGENT);
    if (tid < 8) {
      while (__hip_atomic_load(&cnt[t * 256 + tid * 32],
                               __ATOMIC_RELAXED, __HIP_MEMORY_SCOPE_AGENT) < 4u)
        __builtin_amdgcn_s_sleep(1);
    }
    __syncthreads();
  }
}

// ---------------------------------------------------------------------------
// Suffix scan: A_t = d_t * F_t (in place over dh), ev_b = sum_t A_t.
// One thread per (b, jh).
// ---------------------------------------------------------------------------
__global__ __launch_bounds__(256) void suffix_A(
    float* __restrict__ dh, const float* __restrict__ fh,
    float* __restrict__ evb)
{
  const int g = blockIdx.x * 256 + threadIdx.x;   // 0..16383
  const int b = g >> 9, jh = g & 511;
  float F = 1.f, s0 = 0.f, s1 = 0.f, s2 = 0.f;
  for (int t = 127; t >= 0; --t) {
    size_t db = (size_t)t * 49152 + (size_t)b * 1536 + jh;
    float a0 = dh[db] * F, a1 = dh[db + 512] * F, a2 = dh[db + 1024] * F;
    dh[db] = a0; dh[db + 512] = a1; dh[db + 1024] = a2;
    s0 += a0; s1 += a1; s2 += a2;
    F *= fh[(size_t)t * 16384 + (size_t)b * 512 + jh];
  }
  size_t eb = (size_t)b * 1536 + jh;
  evb[eb] = s0; evb[eb + 512] = s1; evb[eb + 1024] = s2;
}

// ---------------------------------------------------------------------------
// Generic strided batched fp32 GEMM: C[m][n] = sum_k A[.]*B[.] (+bias, relu).
// A addr: z*aBatch + m*sAm + k*sAk;  B addr: z*bBatch + n*sBn + k*sBk
// C addr: z*cBatch + (m%M1)*sCm1 + (m/M1)*sCm2 + n
// ---------------------------------------------------------------------------
template <int BM, int BN, int TM, int TN>
__global__ __launch_bounds__(256) void gemm_f32(
    const float* __restrict__ A, const float* __restrict__ B,
    float* __restrict__ C, const float* __restrict__ bias,
    int M, int N, int K,
    long long sAm, long long sAk, long long aBatch,
    long long sBn, long long sBk, long long bBatch,
    long long sCm1, long long sCm2, int M1, long long cBatch,
    int relu)
{
  constexpr int BK = 16;
  __shared__ float As[BK][BM + 4];
  __shared__ float Bs[BK][BN + 4];
  const int tid = threadIdx.x;
  const long long z = blockIdx.z;
  const float* Ab = A + z * aBatch;
  const float* Bb = B + z * bBatch;
  const int m0 = blockIdx.y * BM, n0 = blockIdx.x * BN;
  constexpr int tn_cnt = BN / TN;
  const int tm0 = (tid / tn_cnt) * TM;
  const int tn0 = (tid % tn_cnt) * TN;

  float acc[TM][TN];
#pragma unroll
  for (int i = 0; i < TM; ++i)
#pragma unroll
    for (int j = 0; j < TN; ++j) acc[i][j] = 0.f;

  for (int k0 = 0; k0 < K; k0 += BK) {
    // ---- stage A ----
    if (sAk == 1) {
      for (int m = tid >> 2; m < BM; m += 64) {
        const int kq = (tid & 3) * 4;
        f32x4 v = {0.f, 0.f, 0.f, 0.f};
        if (m0 + m < M) v = *(const f32x4*)(Ab + (long long)(m0 + m) * sAm + (k0 + kq));
        As[kq + 0][m] = v[0]; As[kq + 1][m] = v[1];
        As[kq + 2][m] = v[2]; As[kq + 3][m] = v[3];
      }
    } else {  // sAm == 1
      constexpr int mq_cnt = BM / 4;
      for (int kk = tid / mq_cnt; kk < BK; kk += 256 / mq_cnt) {
        const int mq = (tid % mq_cnt) * 4;
        f32x4 v = {0.f, 0.f, 0.f, 0.f};
        if (m0 + mq < M) v = *(const f32x4*)(Ab + (long long)(k0 + kk) * sAk + (m0 + mq));
        *(f32x4*)&As[kk][mq] = v;
      }
    }
    // ---- stage B ----
    if (sBk == 1) {
      for (int n = tid >> 2; n < BN; n += 64) {
        const int kq = (tid & 3) * 4;
        f32x4 v = {0.f, 0.f, 0.f, 0.f};
        if (n0 + n < N) v = *(const f32x4*)(Bb + (long long)(n0 + n) * sBn + (k0 + kq));
        Bs[kq + 0][n] = v[0]; Bs[kq + 1][n] = v[1];
        Bs[kq + 2][n] = v[2]; Bs[kq + 3][n] = v[3];
      }
    } else {  // sBn == 1
      constexpr int nq_cnt = BN / 4;
      for (int kk = tid / nq_cnt; kk < BK; kk += 256 / nq_cnt) {
        const int nq = (tid % nq_cnt) * 4;
        f32x4 v = {0.f, 0.f, 0.f, 0.f};
        if (n0 + nq < N) v = *(const f32x4*)(Bb + (long long)(k0 + kk) * sBk + (n0 + nq));
        *(f32x4*)&Bs[kk][nq] = v;
      }
    }
    __syncthreads();

#pragma unroll
    for (int kk = 0; kk < BK; ++kk) {
      float a[TM], bb[TN];
      if constexpr (TM == 8) {
        f32x4 a0 = *(const f32x4*)&As[kk][tm0];
        f32x4 a1 = *(const f32x4*)&As[kk][tm0 + 4];
#pragma unroll
        for (int i = 0; i < 4; ++i) { a[i] = a0[i]; a[4 + i] = a1[i]; }
      } else {
#pragma unroll
        for (int i = 0; i < TM; ++i) a[i] = As[kk][tm0 + i];
      }
      if constexpr (TN == 8) {
        f32x4 b0 = *(const f32x4*)&Bs[kk][tn0];
        f32x4 b1 = *(const f32x4*)&Bs[kk][tn0 + 4];
#pragma unroll
        for (int j = 0; j < 4; ++j) { bb[j] = b0[j]; bb[4 + j] = b1[j]; }
      } else {
#pragma unroll
        for (int j = 0; j < TN; ++j) bb[j] = Bs[kk][tn0 + j];
      }
#pragma unroll
      for (int i = 0; i < TM; ++i)
#pragma unroll
        for (int j = 0; j < TN; ++j) acc[i][j] += a[i] * bb[j];
    }
    __syncthreads();
  }

  // ---- epilogue ----
#pragma unroll
  for (int i = 0; i < TM; ++i) {
    const int mg = m0 + tm0 + i;
    if (mg >= M) continue;
    const long long crow = z * cBatch + (long long)(mg % M1) * sCm1 +
                           (long long)(mg / M1) * sCm2;
#pragma unroll
    for (int j = 0; j < TN; ++j) {
      const int ng = n0 + tn0 + j;
      if (ng >= N) continue;
      float v = acc[i][j];
      if (bias) v += bias[ng];
      if (relu) v = fmaxf(v, 0.f);
      C[crow + ng] = v;
    }
  }
}

// ---------------------------------------------------------------------------
extern "C" void kernel_launch(void* const* d_in, const int* in_sizes, int n_in,
                              void* d_out, int out_size, void* d_ws, size_t ws_size,
                              hipStream_t stream) {
  const float* x   = (const float*)d_in[0];
  const float* Wih = (const float*)d_in[1];
  const float* Whh = (const float*)d_in[2];
  const float* bl  = (const float*)d_in[3];
  const float* Wd  = (const float*)d_in[4];
  const float* bd  = (const float*)d_in[5];
  const float* Ws1 = (const float*)d_in[6];
  const float* bs1 = (const float*)d_in[7];
  const float* Ws2 = (const float*)d_in[8];
  const float* bs2 = (const float*)d_in[9];
  const float* Ws3 = (const float*)d_in[10];
  const float* bs3 = (const float*)d_in[11];
  const float* Ws4 = (const float*)d_in[12];
  const float* bs4 = (const float*)d_in[13];

  float* out = (float*)d_out;
  float* ws  = (float*)d_ws;

  // d_out layout (floats)
  const long long OP = 0, OS = 320, OEX = 16704, OEH = 12599616, OEB = 37765440;

  // scratch inside ev_h output region (dead before final ev_h GEMM writes it)
  float* XW = out + OEH;                              // [128][32][2048]
  float* fh = out + OEH + 8388608;                    // [128][32][512]
  unsigned* Hp = (unsigned*)(out + OEH + 10485760);   // [129][32][512] packed

  // ws scratch (~34 MB)
  float* dh = ws;                       // [128][32][1536]  d -> A in place
  float* Hf = ws + 6291456;             // [129][32][512] fp32
  float* z1 = ws + 8404992;             // [32][512]
  float* z2 = ws + 8421376;             // [32][256]
  float* z3 = ws + 8429568;             // [32][128]
  unsigned* cnt = (unsigned*)(ws + 8433664); // [128][8] stride-32 = 32768 u32

  hipMemsetAsync(cnt, 0, 131072, stream);
  hipMemsetAsync(Hf,  0, 16384 * sizeof(float), stream);    // H[0] = 0
  hipMemsetAsync(Hp,  0, 16384 * sizeof(unsigned), stream);

  dim3 blk(256);

  // K1: XW[t][b][j] = x @ Wih^T + b_lstm   (M=4096 (b,t), N=2048, K=256)
  gemm_f32<128, 128, 8, 8><<<dim3(16, 32, 1), blk, 0, stream>>>(
      x, Wih, XW, bl, 4096, 2048, 256,
      256, 1, 0,            // A: x[m][k]
      256, 1, 0,            // B: Wih[n][k]
      65536, 2048, 128, 0,  // C: XW[t= m%128][b= m/128][n]
      0);

  // K2: persistent recurrence (32 WGs x 512 threads)
  lstm_rec<<<dim3(32), dim3(512), 0, stream>>>(Whh, XW, Hp, Hf, dh, fh, cnt);

  // K3: suffix products, A in place, ev_b
  suffix_A<<<dim3(64), blk, 0, stream>>>(dh, fh, out + OEB);

  // MLP + readout on last = Hf[128]
  const float* hlast = Hf + 2097152;
  gemm_f32<32, 32, 2, 2><<<dim3(16, 1, 1), blk, 0, stream>>>(
      hlast, Ws1, z1, bs1, 32, 512, 512, 512, 1, 0, 512, 1, 0, 512, 0, 32, 0, 1);
  gemm_f32<32, 32, 2, 2><<<dim3(8, 1, 1), blk, 0, stream>>>(
      z1, Ws2, z2, bs2, 32, 256, 512, 512, 1, 0, 512, 1, 0, 256, 0, 32, 0, 1);
  gemm_f32<32, 32, 2, 2><<<dim3(4, 1, 1), blk, 0, stream>>>(
      z2, Ws3, z3, bs3, 32, 128, 256, 256, 1, 0, 256, 1, 0, 128, 0, 32, 0, 1);
  gemm_f32<32, 32, 2, 2><<<dim3(16, 1, 1), blk, 0, stream>>>(
      z3, Ws4, out + OS, bs4, 32, 512, 128, 128, 1, 0, 128, 1, 0, 512, 0, 32, 0, 0);
  gemm_f32<32, 32, 2, 2><<<dim3(1, 1, 1), blk, 0, stream>>>(
      hlast, Wd, out + OP, bd, 32, 10, 512, 512, 1, 0, 512, 1, 0, 10, 0, 32, 0, 0);

  // K4: ev_x[b][j][i] = sum_t A[t][b][j] * x[b][t][i]  (M=1536, N=256, K=128)
  gemm_f32<128, 128, 8, 8><<<dim3(2, 12, 32), blk, 0, stream>>>(
      dh, x, out + OEX, nullptr, 1536, 256, 128,
      1, 49152, 1536,       // A: dh[t][b][j], m=j contiguous
      1, 256, 32768,        // B: x[b][t][i], n=i contiguous
      256, 0, 1536, 393216,
      0);

  // K5: ev_h[b][j][k] = sum_t A[t][b][j] * h_{t-1}[b][k]  (M=1536, N=512, K=128)
  // (runs last: overwrites XW/fh/Hp scratch living in the ev_h region)
  gemm_f32<128, 128, 8, 8><<<dim3(4, 12, 32), blk, 0, stream>>>(
      dh, Hf, out + OEH, nullptr, 1536, 512, 128,
      1, 49152, 1536,       // A: dh[t][b][j]
      1, 16384, 512,        // B: Hf[t][b][k], n=k contiguous
      512, 0, 1536, 786432,
      0);
}

// Round 4
// 947.171 us; speedup vs baseline: 2.9144x; 1.0655x over previous
//
#include <hip/hip_runtime.h>

// ---------------------------------------------------------------------------
// EPROP3_LSTM: e-prop LSTM fwd.  Reformulation:
//   ev_x[b,j,k] = sum_t A_t[b,j] * x_t[b,k],   A_t = d_t * F_t, F_t = prod_{s>t} f_s
//   ev_h[b,j,k] = sum_t A_t[b,j] * h_{t-1}[b,k]
//   ev_b[b,j]   = sum_t A_t[b,j]
// => sequential LSTM recurrence + suffix scan + batched GEMMs (K=T=128).
//
// Round-4: R3 dataflow design with the asm aliasing bug fixed (early-clobber
// "=&v" per load, separate asm statements; poll via __hip_atomic_load).
// Producer wg stores its 2KB h-slice (sc1), vmcnt-drains, sets flag[t+1][wg].
// Consumers poll their 4 producer flags, pull slices sc1, scatter to
// XOR-swizzled LDS hi/lo planes (zero unpack VALU), MFMA, elementwise, store.
// ---------------------------------------------------------------------------

typedef __attribute__((ext_vector_type(8))) short short8;
typedef __attribute__((ext_vector_type(4))) float f32x4;
typedef __attribute__((ext_vector_type(4))) unsigned u32x4;

#define DEV static __device__ __forceinline__

DEV unsigned f2bf(float x) {
  union { float f; unsigned u; } v; v.f = x;
  return (v.u + 0x7fffu + ((v.u >> 16) & 1u)) >> 16;
}
DEV float bf2f(unsigned b) {
  union { float f; unsigned u; } v; v.u = b << 16;
  return v.f;
}

// ---------------------------------------------------------------------------
// Persistent LSTM recurrence.  32 WGs x 512 threads.  WG wg owns hidden units
// jh in [wg*16, wg*16+16) -> 64 gate rows (4 gates x 16).  Whh slice held in
// registers as bf16 hi/lo MFMA B-fragments (3-term split ~= fp32 accuracy).
// ---------------------------------------------------------------------------
__global__ __launch_bounds__(512, 1) void lstm_rec(
    const float* __restrict__ Whh,        // [2048][512]
    const float* __restrict__ XW,         // [128][32][2048]  x@Wih^T + b
    unsigned* __restrict__ Hp,            // [129][32][512] per-producer slices
    float* __restrict__ Hf,               // [129][32][512] fp32 (private)
    float* __restrict__ dh,               // [128][32][1536] (private)
    float* __restrict__ fh,               // [128][32][512] (private)
    unsigned* __restrict__ flags)         // [129][32] u32, pre-zeroed
{
  const int wg   = blockIdx.x;            // 0..31
  const int tid  = threadIdx.x;           // 0..511
  const int lane = tid & 63;
  const int wave = tid >> 6;              // 0..7
  const int tM   = wave & 1;              // batch-tile (0..1)
  const int tN   = wave >> 1;             // row-tile   (0..3)

  __shared__ __align__(16) unsigned Ldh[32 * 256];  // hi bf16 pairs [be][kp]
  __shared__ __align__(16) unsigned Ldl[32 * 256];  // lo bf16 pairs
  __shared__ float gl[32][68];                      // gates tile [b][r]

  const int cc = lane & 15;
  const int kb = lane >> 4;

  // ---- load Whh B-fragments once (hi/lo bf16 split) ----
  const int rloc  = tN * 16 + cc;                              // local row 0..63
  const int jglob = (rloc >> 4) * 512 + wg * 16 + (rloc & 15); // global gate row
  short8 whi[16], wlo[16];
#pragma unroll
  for (int s = 0; s < 16; ++s) {
    const float* wp = Whh + (size_t)jglob * 512 + s * 32 + kb * 8;
    f32x4 w0 = *(const f32x4*)wp;
    f32x4 w1 = *(const f32x4*)(wp + 4);
    short8 hi, lo;
#pragma unroll
    for (int j = 0; j < 4; ++j) {
      unsigned h0 = f2bf(w0[j]);
      hi[j] = (short)h0;  lo[j] = (short)f2bf(w0[j] - bf2f(h0));
      unsigned h1 = f2bf(w1[j]);
      hi[4 + j] = (short)h1;  lo[4 + j] = (short)f2bf(w1[j] - bf2f(h1));
    }
    whi[s] = hi; wlo[s] = lo;
  }

  // MFMA A-fragment LDS read base (dword index), XOR-swizzled:
  // logical chunk c = s*4+kb at row bA lives at dword bA*256 + ((c^(bA&7))<<2)
  const int bA = tM * 16 + cc;
  const int mz = bA & 7;
  const unsigned rbase = (unsigned)(bA * 256 + ((kb ^ (mz & 3)) << 2) + ((mz >> 2) << 4));

  // staging write mapping (per lane): row beW, chunk c ^ (beW&7)
  const int beW = lane >> 1;
  const int swz = beW & 7;

  const int be = tid >> 4;          // elementwise: batch 0..31
  const int jo = tid & 15;          // elementwise: local hidden unit 0..15
  const int jh = wg * 16 + jo;      // global hidden unit
  float c_reg = 0.f;

  for (int t = 0; t < 128; ++t) {
    // ---- XW prefetch (plain loads; complete under the poll) ----
    const float* xwp = XW + (size_t)t * 65536 + (size_t)be * 2048 + wg * 16 + jo;
    float xwi = xwp[0], xwf = xwp[512], xwg = xwp[1024], xwo = xwp[1536];

    if (t > 0) {
      // ---- poll this wave's 4 producer flags (two u64 sc1 loads) ----
      const unsigned long long* fl =
          (const unsigned long long*)(flags + t * 32 + wave * 4);
      for (;;) {
        unsigned long long f0 = __hip_atomic_load(fl, __ATOMIC_RELAXED,
                                                  __HIP_MEMORY_SCOPE_AGENT);
        unsigned long long f1 = __hip_atomic_load(fl + 1, __ATOMIC_RELAXED,
                                                  __HIP_MEMORY_SCOPE_AGENT);
        unsigned long long v = f0 & f1;
        if (v & (v >> 32) & 1ull) break;
        __builtin_amdgcn_s_sleep(1);
      }

      // ---- pull 4 producer slices (2KB each: 256 hi + 256 lo dwords) ----
      const unsigned* sp = Hp + ((size_t)t * 32 + wave * 4) * 512 + lane * 4;
      u32x4 h0, l0, h1, l1, h2, l2, h3, l3;
#define SLICE_LOAD(dst, addr)                                          \
      asm volatile("global_load_dwordx4 %0, %1, off sc0 sc1"           \
                   : "=&v"(dst) : "v"(addr) : "memory")
      SLICE_LOAD(h0, sp);
      SLICE_LOAD(l0, sp + 256);
      SLICE_LOAD(h1, sp + 512);
      SLICE_LOAD(l1, sp + 768);
      SLICE_LOAD(h2, sp + 1024);
      SLICE_LOAD(l2, sp + 1280);
      SLICE_LOAD(h3, sp + 1536);
      SLICE_LOAD(l3, sp + 1792);
#undef SLICE_LOAD
      asm volatile("s_waitcnt vmcnt(0)" ::: "memory");
      __builtin_amdgcn_sched_barrier(0);

      // ---- scatter to swizzled LDS tiles (b128 writes) ----
      const int c0 = wave * 8 + (lane & 1);   // producer (wave*4+i) -> chunk c0+2i
      const unsigned wb = (unsigned)(beW * 256);
      *(u32x4*)&Ldh[wb + (((c0 + 0) ^ swz) << 2)] = h0;
      *(u32x4*)&Ldl[wb + (((c0 + 0) ^ swz) << 2)] = l0;
      *(u32x4*)&Ldh[wb + (((c0 + 2) ^ swz) << 2)] = h1;
      *(u32x4*)&Ldl[wb + (((c0 + 2) ^ swz) << 2)] = l1;
      *(u32x4*)&Ldh[wb + (((c0 + 4) ^ swz) << 2)] = h2;
      *(u32x4*)&Ldl[wb + (((c0 + 4) ^ swz) << 2)] = l2;
      *(u32x4*)&Ldh[wb + (((c0 + 6) ^ swz) << 2)] = h3;
      *(u32x4*)&Ldl[wb + (((c0 + 6) ^ swz) << 2)] = l3;
    }
    __syncthreads();

    // ---- MFMA: gates_tile = H[t] @ Whh_slice^T (hi/lo 3-term split) ----
    f32x4 acc = {0.f, 0.f, 0.f, 0.f};
    if (t > 0) {
#pragma unroll
      for (int s = 0; s < 16; ++s) {
        const unsigned idx = rbase ^ (unsigned)(s << 4);
        short8 ah = __builtin_bit_cast(short8, *(const u32x4*)&Ldh[idx]);
        short8 al = __builtin_bit_cast(short8, *(const u32x4*)&Ldl[idx]);
        acc = __builtin_amdgcn_mfma_f32_16x16x32_bf16(ah, whi[s], acc, 0, 0, 0);
        acc = __builtin_amdgcn_mfma_f32_16x16x32_bf16(ah, wlo[s], acc, 0, 0, 0);
        acc = __builtin_amdgcn_mfma_f32_16x16x32_bf16(al, whi[s], acc, 0, 0, 0);
      }
    }
    // D layout: row m = 16*tM + 4*(lane>>4)+r (batch), col n = 16*tN + (lane&15)
#pragma unroll
    for (int r = 0; r < 4; ++r)
      gl[tM * 16 + kb * 4 + r][tN * 16 + cc] = acc[r];
    __syncthreads();

    // ---- elementwise LSTM update: thread = (batch be, unit jo) ----
    {
      float pi = xwi + gl[be][jo];
      float pf = xwf + gl[be][16 + jo];
      float pg = xwg + gl[be][32 + jo];
      float po = xwo + gl[be][48 + jo];
      float ig = 1.f / (1.f + expf(-pi));
      float fg = 1.f / (1.f + expf(-pf));
      float gg = tanhf(pg);
      float og = 1.f / (1.f + expf(-po));
      float di = gg * ig * (1.f - ig);
      float df = c_reg * fg * (1.f - fg);     // uses c_{t-1}
      float dg = ig * (1.f - gg * gg);
      c_reg = fg * c_reg + ig * gg;
      float hn = og * tanhf(c_reg);
      Hf[(size_t)(t + 1) * 16384 + (size_t)be * 512 + jh] = hn;
      size_t db = (size_t)t * 49152 + (size_t)be * 1536 + jh;
      dh[db] = di; dh[db + 512] = df; dh[db + 1024] = dg;
      fh[(size_t)t * 16384 + (size_t)be * 512 + jh] = fg;

      // pack bf16 hi/lo pairs with neighbor lane, store slice (sc1)
      unsigned hh = f2bf(hn);
      unsigned hl = f2bf(hn - bf2f(hh));
      unsigned hh_nb = (unsigned)__shfl_xor((int)hh, 1);
      unsigned hl_nb = (unsigned)__shfl_xor((int)hl, 1);
      size_t sb = ((size_t)(t + 1) * 32 + wg) * 512;
      unsigned stv; size_t sa;
      if (tid & 1) { stv = hl_nb | (hl << 16); sa = sb + 256 + (tid >> 1); }
      else         { stv = hh | (hh_nb << 16); sa = sb + (tid >> 1); }
      __hip_atomic_store(&Hp[sa], stv, __ATOMIC_RELAXED, __HIP_MEMORY_SCOPE_AGENT);
    }

    // ---- drain slice stores, then publish flag (the only sync) ----
    asm volatile("s_waitcnt vmcnt(0)" ::: "memory");
    __syncthreads();
    if (tid == 0)
      __hip_atomic_store(&flags[(t + 1) * 32 + wg], 1u,
                         __ATOMIC_RELAXED, __HIP_MEMORY_SCOPE_AGENT);
  }
}

// ---------------------------------------------------------------------------
// Suffix scan, 4-way chunked over t.
// pre:  Cp[k][b][jh] = prod_{t in chunk k} f_t
// main: per chunk k, F = prod_{k'>k} Cp[k'], scan 32 steps, A in place,
//       partial sums -> Sp[k][b][gate][jh]
// red:  evb = sum_k Sp[k]
// ---------------------------------------------------------------------------
__global__ __launch_bounds__(256) void suffix_pre(
    const float* __restrict__ fh, float* __restrict__ Cp)
{
  const int g = blockIdx.x * 256 + threadIdx.x;   // 0..65535 = (k,b,jh)
  const int k = g >> 14, bjh = g & 16383;
  const int b = bjh >> 9, jh = bjh & 511;
  float P = 1.f;
  for (int t = k * 32; t < k * 32 + 32; ++t)
    P *= fh[(size_t)t * 16384 + (size_t)b * 512 + jh];
  Cp[g] = P;
}

__global__ __launch_bounds__(256) void suffix_main(
    float* __restrict__ dh, const float* __restrict__ fh,
    const float* __restrict__ Cp, float* __restrict__ Sp)
{
  const int g = blockIdx.x * 256 + threadIdx.x;   // (k,b,jh)
  const int k = g >> 14, bjh = g & 16383;
  const int b = bjh >> 9, jh = bjh & 511;
  float F = 1.f;
  for (int k2 = k + 1; k2 < 4; ++k2) F *= Cp[(k2 << 14) | bjh];
  float s0 = 0.f, s1 = 0.f, s2 = 0.f;
  for (int t = k * 32 + 31; t >= k * 32; --t) {
    size_t db = (size_t)t * 49152 + (size_t)b * 1536 + jh;
    float a0 = dh[db] * F, a1 = dh[db + 512] * F, a2 = dh[db + 1024] * F;
    dh[db] = a0; dh[db + 512] = a1; dh[db + 1024] = a2;
    s0 += a0; s1 += a1; s2 += a2;
    F *= fh[(size_t)t * 16384 + (size_t)b * 512 + jh];
  }
  size_t sb = (size_t)(k * 32 + b) * 1536 + jh;
  Sp[sb] = s0; Sp[sb + 512] = s1; Sp[sb + 1024] = s2;
}

__global__ __launch_bounds__(256) void evb_reduce(
    const float* __restrict__ Sp, float* __restrict__ evb)
{
  const int g = blockIdx.x * 256 + threadIdx.x;   // 0..49151
  evb[g] = Sp[g] + Sp[49152 + g] + Sp[98304 + g] + Sp[147456 + g];
}

// ---------------------------------------------------------------------------
// Generic strided batched fp32 GEMM.
// A addr: z*aBatch + m*sAm + k*sAk;  B addr: z*bBatch + n*sBn + k*sBk
// C addr: z*cBatch + (m%M1)*sCm1 + (m/M1)*sCm2 + n
// ---------------------------------------------------------------------------
template <int BM, int BN, int TM, int TN>
__global__ __launch_bounds__(256) void gemm_f32(
    const float* __restrict__ A, const float* __restrict__ B,
    float* __restrict__ C, const float* __restrict__ bias,
    int M, int N, int K,
    long long sAm, long long sAk, long long aBatch,
    long long sBn, long long sBk, long long bBatch,
    long long sCm1, long long sCm2, int M1, long long cBatch,
    int relu)
{
  constexpr int BK = 16;
  __shared__ float As[BK][BM + 4];
  __shared__ float Bs[BK][BN + 4];
  const int tid = threadIdx.x;
  const long long z = blockIdx.z;
  const float* Ab = A + z * aBatch;
  const float* Bb = B + z * bBatch;
  const int m0 = blockIdx.y * BM, n0 = blockIdx.x * BN;
  constexpr int tn_cnt = BN / TN;
  const int tm0 = (tid / tn_cnt) * TM;
  const int tn0 = (tid % tn_cnt) * TN;

  float acc[TM][TN];
#pragma unroll
  for (int i = 0; i < TM; ++i)
#pragma unroll
    for (int j = 0; j < TN; ++j) acc[i][j] = 0.f;

  for (int k0 = 0; k0 < K; k0 += BK) {
    if (sAk == 1) {
      for (int m = tid >> 2; m < BM; m += 64) {
        const int kq = (tid & 3) * 4;
        f32x4 v = {0.f, 0.f, 0.f, 0.f};
        if (m0 + m < M) v = *(const f32x4*)(Ab + (long long)(m0 + m) * sAm + (k0 + kq));
        As[kq + 0][m] = v[0]; As[kq + 1][m] = v[1];
        As[kq + 2][m] = v[2]; As[kq + 3][m] = v[3];
      }
    } else {
      constexpr int mq_cnt = BM / 4;
      for (int kk = tid / mq_cnt; kk < BK; kk += 256 / mq_cnt) {
        const int mq = (tid % mq_cnt) * 4;
        f32x4 v = {0.f, 0.f, 0.f, 0.f};
        if (m0 + mq < M) v = *(const f32x4*)(Ab + (long long)(k0 + kk) * sAk + (m0 + mq));
        *(f32x4*)&As[kk][mq] = v;
      }
    }
    if (sBk == 1) {
      for (int n = tid >> 2; n < BN; n += 64) {
        const int kq = (tid & 3) * 4;
        f32x4 v = {0.f, 0.f, 0.f, 0.f};
        if (n0 + n < N) v = *(const f32x4*)(Bb + (long long)(n0 + n) * sBn + (k0 + kq));
        Bs[kq + 0][n] = v[0]; Bs[kq + 1][n] = v[1];
        Bs[kq + 2][n] = v[2]; Bs[kq + 3][n] = v[3];
      }
    } else {
      constexpr int nq_cnt = BN / 4;
      for (int kk = tid / nq_cnt; kk < BK; kk += 256 / nq_cnt) {
        const int nq = (tid % nq_cnt) * 4;
        f32x4 v = {0.f, 0.f, 0.f, 0.f};
        if (n0 + nq < N) v = *(const f32x4*)(Bb + (long long)(k0 + kk) * sBk + (n0 + nq));
        *(f32x4*)&Bs[kk][nq] = v;
      }
    }
    __syncthreads();

#pragma unroll
    for (int kk = 0; kk < BK; ++kk) {
      float a[TM], bb[TN];
      if constexpr (TM == 8) {
        f32x4 a0 = *(const f32x4*)&As[kk][tm0];
        f32x4 a1 = *(const f32x4*)&As[kk][tm0 + 4];
#pragma unroll
        for (int i = 0; i < 4; ++i) { a[i] = a0[i]; a[4 + i] = a1[i]; }
      } else {
#pragma unroll
        for (int i = 0; i < TM; ++i) a[i] = As[kk][tm0 + i];
      }
      if constexpr (TN == 8) {
        f32x4 b0 = *(const f32x4*)&Bs[kk][tn0];
        f32x4 b1 = *(const f32x4*)&Bs[kk][tn0 + 4];
#pragma unroll
        for (int j = 0; j < 4; ++j) { bb[j] = b0[j]; bb[4 + j] = b1[j]; }
      } else {
#pragma unroll
        for (int j = 0; j < TN; ++j) bb[j] = Bs[kk][tn0 + j];
      }
#pragma unroll
      for (int i = 0; i < TM; ++i)
#pragma unroll
        for (int j = 0; j < TN; ++j) acc[i][j] += a[i] * bb[j];
    }
    __syncthreads();
  }

#pragma unroll
  for (int i = 0; i < TM; ++i) {
    const int mg = m0 + tm0 + i;
    if (mg >= M) continue;
    const long long crow = z * cBatch + (long long)(mg % M1) * sCm1 +
                           (long long)(mg / M1) * sCm2;
#pragma unroll
    for (int j = 0; j < TN; ++j) {
      const int ng = n0 + tn0 + j;
      if (ng >= N) continue;
      float v = acc[i][j];
      if (bias) v += bias[ng];
      if (relu) v = fmaxf(v, 0.f);
      C[crow + ng] = v;
    }
  }
}

// ---------------------------------------------------------------------------
extern "C" void kernel_launch(void* const* d_in, const int* in_sizes, int n_in,
                              void* d_out, int out_size, void* d_ws, size_t ws_size,
                              hipStream_t stream) {
  const float* x   = (const float*)d_in[0];
  const float* Wih = (const float*)d_in[1];
  const float* Whh = (const float*)d_in[2];
  const float* bl  = (const float*)d_in[3];
  const float* Wd  = (const float*)d_in[4];
  const float* bd  = (const float*)d_in[5];
  const float* Ws1 = (const float*)d_in[6];
  const float* bs1 = (const float*)d_in[7];
  const float* Ws2 = (const float*)d_in[8];
  const float* bs2 = (const float*)d_in[9];
  const float* Ws3 = (const float*)d_in[10];
  const float* bs3 = (const float*)d_in[11];
  const float* Ws4 = (const float*)d_in[12];
  const float* bs4 = (const float*)d_in[13];

  float* out = (float*)d_out;
  float* ws  = (float*)d_ws;

  // d_out layout (floats)
  const long long OP = 0, OS = 320, OEX = 16704, OEH = 12599616, OEB = 37765440;

  // scratch inside ev_h output region (dead before final ev_h GEMM writes it)
  float* XW = out + OEH;                              // [128][32][2048]
  float* fh = out + OEH + 8388608;                    // [128][32][512]
  unsigned* Hp = (unsigned*)(out + OEH + 10485760);   // [129][32][512] slices
  float* Cp = out + OEH + 12599296;                   // [4][32][512]
  float* Sp = out + OEH + 12664832;                   // [4][32][1536]

  // ws scratch
  float* dh = ws;                       // [128][32][1536]  d -> A in place
  float* Hf = ws + 6291456;             // [129][32][512] fp32
  float* z1 = ws + 8404992;             // [32][512]
  float* z2 = ws + 8421376;             // [32][256]
  float* z3 = ws + 8429568;             // [32][128]
  unsigned* flags = (unsigned*)(ws + 8433664);  // [129][32]

  hipMemsetAsync(flags, 0, 129 * 32 * sizeof(unsigned), stream);
  hipMemsetAsync(Hf, 0, 16384 * sizeof(float), stream);    // H[0] = 0

  dim3 blk(256);

  // K1: XW[t][b][j] = x @ Wih^T + b_lstm   (M=4096 (b,t), N=2048, K=256)
  gemm_f32<128, 128, 8, 8><<<dim3(16, 32, 1), blk, 0, stream>>>(
      x, Wih, XW, bl, 4096, 2048, 256,
      256, 1, 0, 256, 1, 0, 65536, 2048, 128, 0, 0);

  // K2: persistent recurrence (32 WGs x 512 threads, dataflow flags)
  lstm_rec<<<dim3(32), dim3(512), 0, stream>>>(Whh, XW, Hp, Hf, dh, fh, flags);

  // K3: chunked suffix products, A in place, ev_b
  suffix_pre<<<dim3(256), blk, 0, stream>>>(fh, Cp);
  suffix_main<<<dim3(256), blk, 0, stream>>>(dh, fh, Cp, Sp);
  evb_reduce<<<dim3(192), blk, 0, stream>>>(Sp, out + OEB);

  // MLP + readout on last = Hf[128]
  const float* hlast = Hf + 2097152;
  gemm_f32<32, 32, 2, 2><<<dim3(16, 1, 1), blk, 0, stream>>>(
      hlast, Ws1, z1, bs1, 32, 512, 512, 512, 1, 0, 512, 1, 0, 512, 0, 32, 0, 1);
  gemm_f32<32, 32, 2, 2><<<dim3(8, 1, 1), blk, 0, stream>>>(
      z1, Ws2, z2, bs2, 32, 256, 512, 512, 1, 0, 512, 1, 0, 256, 0, 32, 0, 1);
  gemm_f32<32, 32, 2, 2><<<dim3(4, 1, 1), blk, 0, stream>>>(
      z2, Ws3, z3, bs3, 32, 128, 256, 256, 1, 0, 256, 1, 0, 128, 0, 32, 0, 1);
  gemm_f32<32, 32, 2, 2><<<dim3(16, 1, 1), blk, 0, stream>>>(
      z3, Ws4, out + OS, bs4, 32, 512, 128, 128, 1, 0, 128, 1, 0, 512, 0, 32, 0, 0);
  gemm_f32<32, 32, 2, 2><<<dim3(1, 1, 1), blk, 0, stream>>>(
      hlast, Wd, out + OP, bd, 32, 10, 512, 512, 1, 0, 512, 1, 0, 10, 0, 32, 0, 0);

  // K4: ev_x[b][j][i] = sum_t A[t][b][j] * x[b][t][i]  (M=1536, N=256, K=128)
  gemm_f32<128, 128, 8, 8><<<dim3(2, 12, 32), blk, 0, stream>>>(
      dh, x, out + OEX, nullptr, 1536, 256, 128,
      1, 49152, 1536, 1, 256, 32768, 256, 0, 1536, 393216, 0);

  // K5: ev_h[b][j][k] = sum_t A[t][b][j] * h_{t-1}[b][k]  (M=1536, N=512, K=128)
  // (runs last: overwrites XW/fh/Hp/Cp/Sp scratch living in the ev_h region)
  gemm_f32<128, 128, 8, 8><<<dim3(4, 12, 32), blk, 0, stream>>>(
      dh, Hf, out + OEH, nullptr, 1536, 512, 128,
      1, 49152, 1536, 1, 16384, 512, 512, 0, 1536, 786432, 0);
}

// Round 7
// 775.783 us; speedup vs baseline: 3.5582x; 1.2209x over previous
//
#include <hip/hip_runtime.h>

// ---------------------------------------------------------------------------
// EPROP3_LSTM: e-prop LSTM fwd.  Reformulation:
//   ev_x[b,j,k] = sum_t A_t[b,j] * x_t[b,k],   A_t = d_t * F_t, F_t = prod_{s>t} f_s
//   ev_h[b,j,k] = sum_t A_t[b,j] * h_{t-1}[b,k]
//   ev_b[b,j]   = sum_t A_t[b,j]
// => sequential LSTM recurrence + suffix scan + batched GEMMs (K=T=128).
//
// Round-7: R6 with the packpair reference-binding compile error fixed
// (return {hi,lo} by value; vector-element assignment is legal, reference
// binding is not).  Recurrence = proven R4 kernel.  K1/K4/K5 on matrix cores
// via bf16 hi/lo 3-term split (Ah*Bh + Ah*Bl + Al*Bh ~= fp32 accuracy).
// ---------------------------------------------------------------------------

typedef __attribute__((ext_vector_type(8))) short short8;
typedef __attribute__((ext_vector_type(4))) float f32x4;
typedef __attribute__((ext_vector_type(4))) unsigned u32x4;

#define DEV static __device__ __forceinline__

DEV unsigned f2bf(float x) {
  union { float f; unsigned u; } v; v.f = x;
  return (v.u + 0x7fffu + ((v.u >> 16) & 1u)) >> 16;
}
DEV float bf2f(unsigned b) {
  union { float f; unsigned u; } v; v.u = b << 16;
  return v.f;
}
struct HiLo { unsigned hi, lo; };
// pack two floats into (hi-bf16 pair, lo-bf16 pair)
DEV HiLo packpair(float a, float b) {
  unsigned ha = f2bf(a), hb = f2bf(b);
  unsigned la = f2bf(a - bf2f(ha)), lb = f2bf(b - bf2f(hb));
  HiLo r; r.hi = ha | (hb << 16); r.lo = la | (lb << 16);
  return r;
}

// ---------------------------------------------------------------------------
// Persistent LSTM recurrence (EXACT round-4 kernel, proven).  32 WGs x 512.
// ---------------------------------------------------------------------------
__global__ __launch_bounds__(512, 1) void lstm_rec(
    const float* __restrict__ Whh,        // [2048][512]
    const float* __restrict__ XW,         // [128][32][2048]  x@Wih^T + b
    unsigned* __restrict__ Hp,            // [129][32][512] per-producer slices
    float* __restrict__ Hf,               // [129][32][512] fp32 (private)
    float* __restrict__ dh,               // [128][32][1536] (private)
    float* __restrict__ fh,               // [128][32][512] (private)
    unsigned* __restrict__ flags)         // [129][32] u32, pre-zeroed
{
  const int wg   = blockIdx.x;            // 0..31
  const int tid  = threadIdx.x;           // 0..511
  const int lane = tid & 63;
  const int wave = tid >> 6;              // 0..7
  const int tM   = wave & 1;              // batch-tile (0..1)
  const int tN   = wave >> 1;             // row-tile   (0..3)

  __shared__ __align__(16) unsigned Ldh[32 * 256];  // hi bf16 pairs [be][kp]
  __shared__ __align__(16) unsigned Ldl[32 * 256];  // lo bf16 pairs
  __shared__ float gl[32][68];                      // gates tile [b][r]

  const int cc = lane & 15;
  const int kb = lane >> 4;

  // ---- load Whh B-fragments once (hi/lo bf16 split) ----
  const int rloc  = tN * 16 + cc;                              // local row 0..63
  const int jglob = (rloc >> 4) * 512 + wg * 16 + (rloc & 15); // global gate row
  short8 whi[16], wlo[16];
#pragma unroll
  for (int s = 0; s < 16; ++s) {
    const float* wp = Whh + (size_t)jglob * 512 + s * 32 + kb * 8;
    f32x4 w0 = *(const f32x4*)wp;
    f32x4 w1 = *(const f32x4*)(wp + 4);
    short8 hi, lo;
#pragma unroll
    for (int j = 0; j < 4; ++j) {
      unsigned h0 = f2bf(w0[j]);
      hi[j] = (short)h0;  lo[j] = (short)f2bf(w0[j] - bf2f(h0));
      unsigned h1 = f2bf(w1[j]);
      hi[4 + j] = (short)h1;  lo[4 + j] = (short)f2bf(w1[j] - bf2f(h1));
    }
    whi[s] = hi; wlo[s] = lo;
  }

  // MFMA A-fragment LDS read base (dword index), XOR-swizzled
  const int bA = tM * 16 + cc;
  const int mz = bA & 7;
  const unsigned rbase = (unsigned)(bA * 256 + ((kb ^ (mz & 3)) << 2) + ((mz >> 2) << 4));

  // staging write mapping (per lane): row beW, chunk c ^ (beW&7)
  const int beW = lane >> 1;
  const int swz = beW & 7;

  const int be = tid >> 4;          // elementwise: batch 0..31
  const int jo = tid & 15;          // elementwise: local hidden unit 0..15
  const int jh = wg * 16 + jo;      // global hidden unit
  float c_reg = 0.f;

  for (int t = 0; t < 128; ++t) {
    // ---- XW prefetch (plain loads; complete under the poll) ----
    const float* xwp = XW + (size_t)t * 65536 + (size_t)be * 2048 + wg * 16 + jo;
    float xwi = xwp[0], xwf = xwp[512], xwg = xwp[1024], xwo = xwp[1536];

    if (t > 0) {
      // ---- poll this wave's 4 producer flags (two u64 sc1 loads) ----
      const unsigned long long* fl =
          (const unsigned long long*)(flags + t * 32 + wave * 4);
      for (;;) {
        unsigned long long f0 = __hip_atomic_load(fl, __ATOMIC_RELAXED,
                                                  __HIP_MEMORY_SCOPE_AGENT);
        unsigned long long f1 = __hip_atomic_load(fl + 1, __ATOMIC_RELAXED,
                                                  __HIP_MEMORY_SCOPE_AGENT);
        unsigned long long v = f0 & f1;
        if (v & (v >> 32) & 1ull) break;
        __builtin_amdgcn_s_sleep(1);
      }

      // ---- pull 4 producer slices (2KB each: 256 hi + 256 lo dwords) ----
      const unsigned* sp = Hp + ((size_t)t * 32 + wave * 4) * 512 + lane * 4;
      u32x4 h0, l0, h1, l1, h2, l2, h3, l3;
#define SLICE_LOAD(dst, addr)                                          \
      asm volatile("global_load_dwordx4 %0, %1, off sc0 sc1"           \
                   : "=&v"(dst) : "v"(addr) : "memory")
      SLICE_LOAD(h0, sp);
      SLICE_LOAD(l0, sp + 256);
      SLICE_LOAD(h1, sp + 512);
      SLICE_LOAD(l1, sp + 768);
      SLICE_LOAD(h2, sp + 1024);
      SLICE_LOAD(l2, sp + 1280);
      SLICE_LOAD(h3, sp + 1536);
      SLICE_LOAD(l3, sp + 1792);
#undef SLICE_LOAD
      asm volatile("s_waitcnt vmcnt(0)" ::: "memory");
      __builtin_amdgcn_sched_barrier(0);

      // ---- scatter to swizzled LDS tiles (b128 writes) ----
      const int c0 = wave * 8 + (lane & 1);   // producer (wave*4+i) -> chunk c0+2i
      const unsigned wb = (unsigned)(beW * 256);
      *(u32x4*)&Ldh[wb + (((c0 + 0) ^ swz) << 2)] = h0;
      *(u32x4*)&Ldl[wb + (((c0 + 0) ^ swz) << 2)] = l0;
      *(u32x4*)&Ldh[wb + (((c0 + 2) ^ swz) << 2)] = h1;
      *(u32x4*)&Ldl[wb + (((c0 + 2) ^ swz) << 2)] = l1;
      *(u32x4*)&Ldh[wb + (((c0 + 4) ^ swz) << 2)] = h2;
      *(u32x4*)&Ldl[wb + (((c0 + 4) ^ swz) << 2)] = l2;
      *(u32x4*)&Ldh[wb + (((c0 + 6) ^ swz) << 2)] = h3;
      *(u32x4*)&Ldl[wb + (((c0 + 6) ^ swz) << 2)] = l3;
    }
    __syncthreads();

    // ---- MFMA: gates_tile = H[t] @ Whh_slice^T (hi/lo 3-term split) ----
    f32x4 acc = {0.f, 0.f, 0.f, 0.f};
    if (t > 0) {
#pragma unroll
      for (int s = 0; s < 16; ++s) {
        const unsigned idx = rbase ^ (unsigned)(s << 4);
        short8 ah = __builtin_bit_cast(short8, *(const u32x4*)&Ldh[idx]);
        short8 al = __builtin_bit_cast(short8, *(const u32x4*)&Ldl[idx]);
        acc = __builtin_amdgcn_mfma_f32_16x16x32_bf16(ah, whi[s], acc, 0, 0, 0);
        acc = __builtin_amdgcn_mfma_f32_16x16x32_bf16(ah, wlo[s], acc, 0, 0, 0);
        acc = __builtin_amdgcn_mfma_f32_16x16x32_bf16(al, whi[s], acc, 0, 0, 0);
      }
    }
    // D layout: row m = 16*tM + 4*(lane>>4)+r (batch), col n = 16*tN + (lane&15)
#pragma unroll
    for (int r = 0; r < 4; ++r)
      gl[tM * 16 + kb * 4 + r][tN * 16 + cc] = acc[r];
    __syncthreads();

    // ---- elementwise LSTM update: thread = (batch be, unit jo) ----
    {
      float pi = xwi + gl[be][jo];
      float pf = xwf + gl[be][16 + jo];
      float pg = xwg + gl[be][32 + jo];
      float po = xwo + gl[be][48 + jo];
      float ig = 1.f / (1.f + expf(-pi));
      float fg = 1.f / (1.f + expf(-pf));
      float gg = tanhf(pg);
      float og = 1.f / (1.f + expf(-po));
      float di = gg * ig * (1.f - ig);
      float df = c_reg * fg * (1.f - fg);     // uses c_{t-1}
      float dg = ig * (1.f - gg * gg);
      c_reg = fg * c_reg + ig * gg;
      float hn = og * tanhf(c_reg);
      Hf[(size_t)(t + 1) * 16384 + (size_t)be * 512 + jh] = hn;
      size_t db = (size_t)t * 49152 + (size_t)be * 1536 + jh;
      dh[db] = di; dh[db + 512] = df; dh[db + 1024] = dg;
      fh[(size_t)t * 16384 + (size_t)be * 512 + jh] = fg;

      // pack bf16 hi/lo pairs with neighbor lane, store slice (sc1)
      unsigned hh = f2bf(hn);
      unsigned hl = f2bf(hn - bf2f(hh));
      unsigned hh_nb = (unsigned)__shfl_xor((int)hh, 1);
      unsigned hl_nb = (unsigned)__shfl_xor((int)hl, 1);
      size_t sb = ((size_t)(t + 1) * 32 + wg) * 512;
      unsigned stv; size_t sa;
      if (tid & 1) { stv = hl_nb | (hl << 16); sa = sb + 256 + (tid >> 1); }
      else         { stv = hh | (hh_nb << 16); sa = sb + (tid >> 1); }
      __hip_atomic_store(&Hp[sa], stv, __ATOMIC_RELAXED, __HIP_MEMORY_SCOPE_AGENT);
    }

    // ---- drain slice stores, then publish flag (the only sync) ----
    asm volatile("s_waitcnt vmcnt(0)" ::: "memory");
    __syncthreads();
    if (tid == 0)
      __hip_atomic_store(&flags[(t + 1) * 32 + wg], 1u,
                         __ATOMIC_RELAXED, __HIP_MEMORY_SCOPE_AGENT);
  }
}

// ---------------------------------------------------------------------------
// Suffix scan, 4-way chunked over t.
// ---------------------------------------------------------------------------
__global__ __launch_bounds__(256) void suffix_pre(
    const float* __restrict__ fh, float* __restrict__ Cp)
{
  const int g = blockIdx.x * 256 + threadIdx.x;   // 0..65535 = (k,b,jh)
  const int k = g >> 14, bjh = g & 16383;
  const int b = bjh >> 9, jh = bjh & 511;
  float P = 1.f;
  for (int t = k * 32; t < k * 32 + 32; ++t)
    P *= fh[(size_t)t * 16384 + (size_t)b * 512 + jh];
  Cp[g] = P;
}

__global__ __launch_bounds__(256) void suffix_main(
    float* __restrict__ dh, const float* __restrict__ fh,
    const float* __restrict__ Cp, float* __restrict__ Sp)
{
  const int g = blockIdx.x * 256 + threadIdx.x;   // (k,b,jh)
  const int k = g >> 14, bjh = g & 16383;
  const int b = bjh >> 9, jh = bjh & 511;
  float F = 1.f;
  for (int k2 = k + 1; k2 < 4; ++k2) F *= Cp[(k2 << 14) | bjh];
  float s0 = 0.f, s1 = 0.f, s2 = 0.f;
  for (int t = k * 32 + 31; t >= k * 32; --t) {
    size_t db = (size_t)t * 49152 + (size_t)b * 1536 + jh;
    float a0 = dh[db] * F, a1 = dh[db + 512] * F, a2 = dh[db + 1024] * F;
    dh[db] = a0; dh[db + 512] = a1; dh[db + 1024] = a2;
    s0 += a0; s1 += a1; s2 += a2;
    F *= fh[(size_t)t * 16384 + (size_t)b * 512 + jh];
  }
  size_t sb = (size_t)(k * 32 + b) * 1536 + jh;
  Sp[sb] = s0; Sp[sb + 512] = s1; Sp[sb + 1024] = s2;
}

__global__ __launch_bounds__(256) void evb_reduce(
    const float* __restrict__ Sp, float* __restrict__ evb)
{
  const int g = blockIdx.x * 256 + threadIdx.x;   // 0..49151
  evb[g] = Sp[g] + Sp[49152 + g] + Sp[98304 + g] + Sp[147456 + g];
}

// ---------------------------------------------------------------------------
// bf16 hi/lo-split MFMA GEMM.  128x128 tile, BK=32, 256 threads (4 waves,
// 2x2 wave grid, 64x64 per wave = 4x4 16x16 fragments).  fp32 inputs are
// converted to (hi,lo) bf16 pairs during LDS staging; 3-term MFMA split.
// Requires M%128==0, N%128==0, K%32==0.
// A addr: z*aBatch + m*sAm + k*sAk  (one of sAm,sAk must be 1)
// B addr: z*bBatch + n*sBn + k*sBk  (one of sBn,sBk must be 1)
// C addr: z*cBatch + (m%M1)*sCm1 + (m/M1)*sCm2 + n
// ---------------------------------------------------------------------------
__global__ __launch_bounds__(256, 2) void gemm_bf16s(
    const float* __restrict__ A, const float* __restrict__ B,
    float* __restrict__ C, const float* __restrict__ bias,
    int M, int N, int K,
    long long sAm, long long sAk, long long aBatch,
    long long sBn, long long sBk, long long bBatch,
    long long sCm1, long long sCm2, int M1, long long cBatch)
{
  // row stride 20 u32 (80B): 16 data u32 + 4 pad -> 16B-aligned, ~2-way banks
  __shared__ __align__(16) unsigned Ahi[128 * 20], Alo[128 * 20];
  __shared__ __align__(16) unsigned Bhi[128 * 20], Blo[128 * 20];

  const int tid  = threadIdx.x;
  const int lane = tid & 63;
  const int wave = tid >> 6;
  const int wm   = wave >> 1;             // 0..1
  const int wn   = wave & 1;              // 0..1
  const int cc   = lane & 15;
  const int kb   = lane >> 4;
  const long long z = blockIdx.z;
  const float* Ab = A + z * aBatch;
  const float* Bb = B + z * bBatch;
  const int m0 = blockIdx.y * 128, n0 = blockIdx.x * 128;

  f32x4 acc[4][4];
#pragma unroll
  for (int i = 0; i < 4; ++i)
#pragma unroll
    for (int j = 0; j < 4; ++j) acc[i][j] = (f32x4){0.f, 0.f, 0.f, 0.f};

  for (int k0 = 0; k0 < K; k0 += 32) {
    // ---- stage A ----
    if (sAk == 1) {
      const int r = tid >> 1, half = tid & 1;
      const float* s = Ab + (long long)(m0 + r) * sAm + (k0 + half * 16);
      f32x4 v0 = *(const f32x4*)s;
      f32x4 v1 = *(const f32x4*)(s + 4);
      f32x4 v2 = *(const f32x4*)(s + 8);
      f32x4 v3 = *(const f32x4*)(s + 12);
      u32x4 h0, h1, l0, l1;
      HiLo p;
      p = packpair(v0[0], v0[1]); h0[0] = p.hi; l0[0] = p.lo;
      p = packpair(v0[2], v0[3]); h0[1] = p.hi; l0[1] = p.lo;
      p = packpair(v1[0], v1[1]); h0[2] = p.hi; l0[2] = p.lo;
      p = packpair(v1[2], v1[3]); h0[3] = p.hi; l0[3] = p.lo;
      p = packpair(v2[0], v2[1]); h1[0] = p.hi; l1[0] = p.lo;
      p = packpair(v2[2], v2[3]); h1[1] = p.hi; l1[1] = p.lo;
      p = packpair(v3[0], v3[1]); h1[2] = p.hi; l1[2] = p.lo;
      p = packpair(v3[2], v3[3]); h1[3] = p.hi; l1[3] = p.lo;
      const int o = r * 20 + half * 8;
      *(u32x4*)&Ahi[o] = h0;  *(u32x4*)&Ahi[o + 4] = h1;
      *(u32x4*)&Alo[o] = l0;  *(u32x4*)&Alo[o + 4] = l1;
    } else {  // sAm == 1
#pragma unroll
      for (int it = 0; it < 2; ++it) {
        const int kp = tid >> 4;
        const int mr = (tid & 15) * 4 + it * 64;
        const float* s0 = Ab + (long long)(k0 + 2 * kp) * sAk + (m0 + mr);
        f32x4 va = *(const f32x4*)s0;
        f32x4 vb = *(const f32x4*)(s0 + sAk);
#pragma unroll
        for (int q = 0; q < 4; ++q) {
          HiLo p = packpair(va[q], vb[q]);
          Ahi[(mr + q) * 20 + kp] = p.hi;
          Alo[(mr + q) * 20 + kp] = p.lo;
        }
      }
    }
    // ---- stage B ----
    if (sBk == 1) {
      const int r = tid >> 1, half = tid & 1;
      const float* s = Bb + (long long)(n0 + r) * sBn + (k0 + half * 16);
      f32x4 v0 = *(const f32x4*)s;
      f32x4 v1 = *(const f32x4*)(s + 4);
      f32x4 v2 = *(const f32x4*)(s + 8);
      f32x4 v3 = *(const f32x4*)(s + 12);
      u32x4 h0, h1, l0, l1;
      HiLo p;
      p = packpair(v0[0], v0[1]); h0[0] = p.hi; l0[0] = p.lo;
      p = packpair(v0[2], v0[3]); h0[1] = p.hi; l0[1] = p.lo;
      p = packpair(v1[0], v1[1]); h0[2] = p.hi; l0[2] = p.lo;
      p = packpair(v1[2], v1[3]); h0[3] = p.hi; l0[3] = p.lo;
      p = packpair(v2[0], v2[1]); h1[0] = p.hi; l1[0] = p.lo;
      p = packpair(v2[2], v2[3]); h1[1] = p.hi; l1[1] = p.lo;
      p = packpair(v3[0], v3[1]); h1[2] = p.hi; l1[2] = p.lo;
      p = packpair(v3[2], v3[3]); h1[3] = p.hi; l1[3] = p.lo;
      const int o = r * 20 + half * 8;
      *(u32x4*)&Bhi[o] = h0;  *(u32x4*)&Bhi[o + 4] = h1;
      *(u32x4*)&Blo[o] = l0;  *(u32x4*)&Blo[o + 4] = l1;
    } else {  // sBn == 1
#pragma unroll
      for (int it = 0; it < 2; ++it) {
        const int kp = tid >> 4;
        const int nr = (tid & 15) * 4 + it * 64;
        const float* s0 = Bb + (long long)(k0 + 2 * kp) * sBk + (n0 + nr);
        f32x4 va = *(const f32x4*)s0;
        f32x4 vb = *(const f32x4*)(s0 + sBk);
#pragma unroll
        for (int q = 0; q < 4; ++q) {
          HiLo p = packpair(va[q], vb[q]);
          Bhi[(nr + q) * 20 + kp] = p.hi;
          Blo[(nr + q) * 20 + kp] = p.lo;
        }
      }
    }
    __syncthreads();

    // ---- fragments + MFMA (3-term split) ----
    short8 ah[4], al[4], bh[4], bl[4];
#pragma unroll
    for (int mi = 0; mi < 4; ++mi) {
      const int row = wm * 64 + mi * 16 + cc;
      ah[mi] = __builtin_bit_cast(short8, *(const u32x4*)&Ahi[row * 20 + kb * 4]);
      al[mi] = __builtin_bit_cast(short8, *(const u32x4*)&Alo[row * 20 + kb * 4]);
    }
#pragma unroll
    for (int ni = 0; ni < 4; ++ni) {
      const int row = wn * 64 + ni * 16 + cc;
      bh[ni] = __builtin_bit_cast(short8, *(const u32x4*)&Bhi[row * 20 + kb * 4]);
      bl[ni] = __builtin_bit_cast(short8, *(const u32x4*)&Blo[row * 20 + kb * 4]);
    }
#pragma unroll
    for (int mi = 0; mi < 4; ++mi)
#pragma unroll
      for (int ni = 0; ni < 4; ++ni) {
        acc[mi][ni] = __builtin_amdgcn_mfma_f32_16x16x32_bf16(ah[mi], bh[ni], acc[mi][ni], 0, 0, 0);
        acc[mi][ni] = __builtin_amdgcn_mfma_f32_16x16x32_bf16(ah[mi], bl[ni], acc[mi][ni], 0, 0, 0);
        acc[mi][ni] = __builtin_amdgcn_mfma_f32_16x16x32_bf16(al[mi], bh[ni], acc[mi][ni], 0, 0, 0);
      }
    __syncthreads();
  }

  // ---- epilogue: D row m = (lane>>4)*4 + r, col n = lane&15 ----
#pragma unroll
  for (int ni = 0; ni < 4; ++ni) {
    const int ng = n0 + wn * 64 + ni * 16 + cc;
    const float bv = bias ? bias[ng] : 0.f;
#pragma unroll
    for (int mi = 0; mi < 4; ++mi) {
#pragma unroll
      for (int r = 0; r < 4; ++r) {
        const int mg = m0 + wm * 64 + mi * 16 + kb * 4 + r;
        const long long crow = z * cBatch + (long long)(mg % M1) * sCm1 +
                               (long long)(mg / M1) * sCm2;
        C[crow + ng] = acc[mi][ni][r] + bv;
      }
    }
  }
}

// ---------------------------------------------------------------------------
// Small fp32 GEMM (kept for the tiny MLP/readout layers only).
// ---------------------------------------------------------------------------
template <int BM, int BN, int TM, int TN>
__global__ __launch_bounds__(256) void gemm_f32(
    const float* __restrict__ A, const float* __restrict__ B,
    float* __restrict__ C, const float* __restrict__ bias,
    int M, int N, int K,
    long long sAm, long long sAk, long long aBatch,
    long long sBn, long long sBk, long long bBatch,
    long long sCm1, long long sCm2, int M1, long long cBatch,
    int relu)
{
  constexpr int BK = 16;
  __shared__ float As[BK][BM + 4];
  __shared__ float Bs[BK][BN + 4];
  const int tid = threadIdx.x;
  const long long z = blockIdx.z;
  const float* Ab = A + z * aBatch;
  const float* Bb = B + z * bBatch;
  const int m0 = blockIdx.y * BM, n0 = blockIdx.x * BN;
  constexpr int tn_cnt = BN / TN;
  const int tm0 = (tid / tn_cnt) * TM;
  const int tn0 = (tid % tn_cnt) * TN;

  float acc[TM][TN];
#pragma unroll
  for (int i = 0; i < TM; ++i)
#pragma unroll
    for (int j = 0; j < TN; ++j) acc[i][j] = 0.f;

  for (int k0 = 0; k0 < K; k0 += BK) {
    if (sAk == 1) {
      for (int m = tid >> 2; m < BM; m += 64) {
        const int kq = (tid & 3) * 4;
        f32x4 v = {0.f, 0.f, 0.f, 0.f};
        if (m0 + m < M) v = *(const f32x4*)(Ab + (long long)(m0 + m) * sAm + (k0 + kq));
        As[kq + 0][m] = v[0]; As[kq + 1][m] = v[1];
        As[kq + 2][m] = v[2]; As[kq + 3][m] = v[3];
      }
    } else {
      constexpr int mq_cnt = BM / 4;
      for (int kk = tid / mq_cnt; kk < BK; kk += 256 / mq_cnt) {
        const int mq = (tid % mq_cnt) * 4;
        f32x4 v = {0.f, 0.f, 0.f, 0.f};
        if (m0 + mq < M) v = *(const f32x4*)(Ab + (long long)(k0 + kk) * sAk + (m0 + mq));
        *(f32x4*)&As[kk][mq] = v;
      }
    }
    if (sBk == 1) {
      for (int n = tid >> 2; n < BN; n += 64) {
        const int kq = (tid & 3) * 4;
        f32x4 v = {0.f, 0.f, 0.f, 0.f};
        if (n0 + n < N) v = *(const f32x4*)(Bb + (long long)(n0 + n) * sBn + (k0 + kq));
        Bs[kq + 0][n] = v[0]; Bs[kq + 1][n] = v[1];
        Bs[kq + 2][n] = v[2]; Bs[kq + 3][n] = v[3];
      }
    } else {
      constexpr int nq_cnt = BN / 4;
      for (int kk = tid / nq_cnt; kk < BK; kk += 256 / nq_cnt) {
        const int nq = (tid % nq_cnt) * 4;
        f32x4 v = {0.f, 0.f, 0.f, 0.f};
        if (n0 + nq < N) v = *(const f32x4*)(Bb + (long long)(k0 + kk) * sBk + (n0 + nq));
        *(f32x4*)&Bs[kk][nq] = v;
      }
    }
    __syncthreads();

#pragma unroll
    for (int kk = 0; kk < BK; ++kk) {
      float a[TM], bb[TN];
#pragma unroll
      for (int i = 0; i < TM; ++i) a[i] = As[kk][tm0 + i];
#pragma unroll
      for (int j = 0; j < TN; ++j) bb[j] = Bs[kk][tn0 + j];
#pragma unroll
      for (int i = 0; i < TM; ++i)
#pragma unroll
        for (int j = 0; j < TN; ++j) acc[i][j] += a[i] * bb[j];
    }
    __syncthreads();
  }

#pragma unroll
  for (int i = 0; i < TM; ++i) {
    const int mg = m0 + tm0 + i;
    if (mg >= M) continue;
    const long long crow = z * cBatch + (long long)(mg % M1) * sCm1 +
                           (long long)(mg / M1) * sCm2;
#pragma unroll
    for (int j = 0; j < TN; ++j) {
      const int ng = n0 + tn0 + j;
      if (ng >= N) continue;
      float v = acc[i][j];
      if (bias) v += bias[ng];
      if (relu) v = fmaxf(v, 0.f);
      C[crow + ng] = v;
    }
  }
}

// ---------------------------------------------------------------------------
extern "C" void kernel_launch(void* const* d_in, const int* in_sizes, int n_in,
                              void* d_out, int out_size, void* d_ws, size_t ws_size,
                              hipStream_t stream) {
  const float* x   = (const float*)d_in[0];
  const float* Wih = (const float*)d_in[1];
  const float* Whh = (const float*)d_in[2];
  const float* bl  = (const float*)d_in[3];
  const float* Wd  = (const float*)d_in[4];
  const float* bd  = (const float*)d_in[5];
  const float* Ws1 = (const float*)d_in[6];
  const float* bs1 = (const float*)d_in[7];
  const float* Ws2 = (const float*)d_in[8];
  const float* bs2 = (const float*)d_in[9];
  const float* Ws3 = (const float*)d_in[10];
  const float* bs3 = (const float*)d_in[11];
  const float* Ws4 = (const float*)d_in[12];
  const float* bs4 = (const float*)d_in[13];

  float* out = (float*)d_out;
  float* ws  = (float*)d_ws;

  // d_out layout (floats)
  const long long OP = 0, OS = 320, OEX = 16704, OEH = 12599616, OEB = 37765440;

  // scratch inside ev_h output region (dead before final ev_h GEMM writes it)
  float* XW = out + OEH;                              // [128][32][2048]
  float* fh = out + OEH + 8388608;                    // [128][32][512]
  unsigned* Hp = (unsigned*)(out + OEH + 10485760);   // [129][32][512] slices
  float* Cp = out + OEH + 12599296;                   // [4][32][512]
  float* Sp = out + OEH + 12664832;                   // [4][32][1536]

  // ws scratch
  float* dh = ws;                       // [128][32][1536]  d -> A in place
  float* Hf = ws + 6291456;             // [129][32][512] fp32
  float* z1 = ws + 8404992;             // [32][512]
  float* z2 = ws + 8421376;             // [32][256]
  float* z3 = ws + 8429568;             // [32][128]
  unsigned* flags = (unsigned*)(ws + 8433664);  // [129][32]

  hipMemsetAsync(flags, 0, 129 * 32 * sizeof(unsigned), stream);
  hipMemsetAsync(Hf, 0, 16384 * sizeof(float), stream);    // H[0] = 0

  dim3 blk(256);

  // K1 (MFMA): XW[t][b][j] = x @ Wih^T + b_lstm   (M=4096, N=2048, K=256)
  gemm_bf16s<<<dim3(16, 32, 1), blk, 0, stream>>>(
      x, Wih, XW, bl, 4096, 2048, 256,
      256, 1, 0,            // A: x[m][k], k-contiguous
      256, 1, 0,            // B: Wih[n][k], k-contiguous
      65536, 2048, 128, 0); // C: XW[t=m%128][b=m/128][n]

  // K2: persistent recurrence (32 WGs x 512 threads, dataflow flags)
  lstm_rec<<<dim3(32), dim3(512), 0, stream>>>(Whh, XW, Hp, Hf, dh, fh, flags);

  // K3: chunked suffix products, A in place, ev_b
  suffix_pre<<<dim3(256), blk, 0, stream>>>(fh, Cp);
  suffix_main<<<dim3(256), blk, 0, stream>>>(dh, fh, Cp, Sp);
  evb_reduce<<<dim3(192), blk, 0, stream>>>(Sp, out + OEB);

  // MLP + readout on last = Hf[128] (tiny, fp32)
  const float* hlast = Hf + 2097152;
  gemm_f32<32, 32, 2, 2><<<dim3(16, 1, 1), blk, 0, stream>>>(
      hlast, Ws1, z1, bs1, 32, 512, 512, 512, 1, 0, 512, 1, 0, 512, 0, 32, 0, 1);
  gemm_f32<32, 32, 2, 2><<<dim3(8, 1, 1), blk, 0, stream>>>(
      z1, Ws2, z2, bs2, 32, 256, 512, 512, 1, 0, 512, 1, 0, 256, 0, 32, 0, 1);
  gemm_f32<32, 32, 2, 2><<<dim3(4, 1, 1), blk, 0, stream>>>(
      z2, Ws3, z3, bs3, 32, 128, 256, 256, 1, 0, 256, 1, 0, 128, 0, 32, 0, 1);
  gemm_f32<32, 32, 2, 2><<<dim3(16, 1, 1), blk, 0, stream>>>(
      z3, Ws4, out + OS, bs4, 32, 512, 128, 128, 1, 0, 128, 1, 0, 512, 0, 32, 0, 0);
  gemm_f32<32, 32, 2, 2><<<dim3(1, 1, 1), blk, 0, stream>>>(
      hlast, Wd, out + OP, bd, 32, 10, 512, 512, 1, 0, 512, 1, 0, 10, 0, 32, 0, 0);

  // K4 (MFMA): ev_x[b][j][i] = sum_t A[t][b][j] * x[b][t][i]
  gemm_bf16s<<<dim3(2, 12, 32), blk, 0, stream>>>(
      dh, x, out + OEX, nullptr, 1536, 256, 128,
      1, 49152, 1536,       // A: dh[t][b][j], m=j contiguous
      1, 256, 32768,        // B: x[b][t][i], n=i contiguous
      256, 0, 1536, 393216);

  // K5 (MFMA): ev_h[b][j][k] = sum_t A[t][b][j] * h_{t-1}[b][k]
  // (runs last: overwrites XW/fh/Hp/Cp/Sp scratch living in the ev_h region)
  gemm_bf16s<<<dim3(4, 12, 32), blk, 0, stream>>>(
      dh, Hf, out + OEH, nullptr, 1536, 512, 128,
      1, 49152, 1536,       // A: dh[t][b][j]
      1, 16384, 512,        // B: Hf[t][b][k], n=k contiguous
      512, 0, 1536, 786432);
}

// Round 9
// 774.427 us; speedup vs baseline: 3.5645x; 1.0018x over previous
//
#include <hip/hip_runtime.h>

// ---------------------------------------------------------------------------
// EPROP3_LSTM: e-prop LSTM fwd.  Reformulation:
//   ev_x[b,j,k] = sum_t A_t[b,j] * x_t[b,k],   A_t = d_t * F_t, F_t = prod_{s>t} f_s
//   ev_h[b,j,k] = sum_t A_t[b,j] * h_{t-1}[b,k]
//   ev_b[b,j]   = sum_t A_t[b,j]
// => sequential LSTM recurrence + suffix scan + batched GEMMs (K=T=128).
//
// Round-9: R8 sentinel dataflow with the rule-#18 fix: sched_barrier(0)
// INSIDE the poll loop right after s_waitcnt vmcnt(0), so the sentinel
// compares cannot be hoisted above the wait (R8 exited the poll on stale
// register contents).  Hp pre-filled 0x7F7F7F7F (impossible as packed bf16
// of h in (-1,1) / residuals).  3 independent MFMA accumulator chains.
// K1/K4/K5 on matrix cores via bf16 hi/lo 3-term split (proven in R7).
// ---------------------------------------------------------------------------

typedef __attribute__((ext_vector_type(8))) short short8;
typedef __attribute__((ext_vector_type(4))) float f32x4;
typedef __attribute__((ext_vector_type(4))) unsigned u32x4;

#define DEV static __device__ __forceinline__

DEV unsigned f2bf(float x) {
  union { float f; unsigned u; } v; v.f = x;
  return (v.u + 0x7fffu + ((v.u >> 16) & 1u)) >> 16;
}
DEV float bf2f(unsigned b) {
  union { float f; unsigned u; } v; v.u = b << 16;
  return v.f;
}
struct HiLo { unsigned hi, lo; };
// pack two floats into (hi-bf16 pair, lo-bf16 pair)
DEV HiLo packpair(float a, float b) {
  unsigned ha = f2bf(a), hb = f2bf(b);
  unsigned la = f2bf(a - bf2f(ha)), lb = f2bf(b - bf2f(hb));
  HiLo r; r.hi = ha | (hb << 16); r.lo = la | (lb << 16);
  return r;
}

#define SENT 0x7F7F7F7Fu

// ---------------------------------------------------------------------------
// Persistent LSTM recurrence.  32 WGs x 512 threads.  WG wg owns hidden units
// [wg*16, wg*16+16) -> 64 gate rows.  Whh slice in registers as bf16 hi/lo
// MFMA B-fragments (3-term split ~= fp32 accuracy).  Sentinel dataflow sync.
// ---------------------------------------------------------------------------
__global__ __launch_bounds__(512, 1) void lstm_rec(
    const float* __restrict__ Whh,        // [2048][512]
    const float* __restrict__ XW,         // [128][32][2048]  x@Wih^T + b
    unsigned* __restrict__ Hp,            // [129][32][512] slices, SENT-filled
    float* __restrict__ Hf,               // [129][32][512] fp32 (private)
    float* __restrict__ dh,               // [128][32][1536] (private)
    float* __restrict__ fh)               // [128][32][512] (private)
{
  const int wg   = blockIdx.x;            // 0..31
  const int tid  = threadIdx.x;           // 0..511
  const int lane = tid & 63;
  const int wave = tid >> 6;              // 0..7
  const int tM   = wave & 1;              // batch-tile (0..1)
  const int tN   = wave >> 1;             // row-tile   (0..3)

  __shared__ __align__(16) unsigned Ldh[32 * 256];  // hi bf16 pairs [be][kp]
  __shared__ __align__(16) unsigned Ldl[32 * 256];  // lo bf16 pairs
  __shared__ float gl[32][68];                      // gates tile [b][r]

  const int cc = lane & 15;
  const int kb = lane >> 4;

  // ---- load Whh B-fragments once (hi/lo bf16 split) ----
  const int rloc  = tN * 16 + cc;                              // local row 0..63
  const int jglob = (rloc >> 4) * 512 + wg * 16 + (rloc & 15); // global gate row
  short8 whi[16], wlo[16];
#pragma unroll
  for (int s = 0; s < 16; ++s) {
    const float* wp = Whh + (size_t)jglob * 512 + s * 32 + kb * 8;
    f32x4 w0 = *(const f32x4*)wp;
    f32x4 w1 = *(const f32x4*)(wp + 4);
    short8 hi, lo;
#pragma unroll
    for (int j = 0; j < 4; ++j) {
      unsigned h0 = f2bf(w0[j]);
      hi[j] = (short)h0;  lo[j] = (short)f2bf(w0[j] - bf2f(h0));
      unsigned h1 = f2bf(w1[j]);
      hi[4 + j] = (short)h1;  lo[4 + j] = (short)f2bf(w1[j] - bf2f(h1));
    }
    whi[s] = hi; wlo[s] = lo;
  }

  // MFMA A-fragment LDS read base (dword index), XOR-swizzled
  const int bA = tM * 16 + cc;
  const int mz = bA & 7;
  const unsigned rbase = (unsigned)(bA * 256 + ((kb ^ (mz & 3)) << 2) + ((mz >> 2) << 4));

  // staging write mapping (per lane): row beW, chunk c ^ (beW&7)
  const int beW = lane >> 1;
  const int swz = beW & 7;

  const int be = tid >> 4;          // elementwise: batch 0..31
  const int jo = tid & 15;          // elementwise: local hidden unit 0..15
  const int jh = wg * 16 + jo;      // global hidden unit
  float c_reg = 0.f;

  for (int t = 0; t < 128; ++t) {
    // ---- XW prefetch (plain loads; complete under the poll) ----
    const float* xwp = XW + (size_t)t * 65536 + (size_t)be * 2048 + wg * 16 + jo;
    float xwi = xwp[0], xwf = xwp[512], xwg = xwp[1024], xwo = xwp[1536];

    if (t > 0) {
      // ---- poll the DATA of this wave's 4 producers until sentinel-free ----
      const unsigned* sp = Hp + ((size_t)t * 32 + wave * 4) * 512 + lane * 4;
      u32x4 h0, l0, h1, l1, h2, l2, h3, l3;
      for (;;) {
#define SLICE_LOAD(dst, addr)                                          \
        asm volatile("global_load_dwordx4 %0, %1, off sc0 sc1"         \
                     : "=&v"(dst) : "v"(addr) : "memory")
        SLICE_LOAD(h0, sp);
        SLICE_LOAD(l0, sp + 256);
        SLICE_LOAD(h1, sp + 512);
        SLICE_LOAD(l1, sp + 768);
        SLICE_LOAD(h2, sp + 1024);
        SLICE_LOAD(l2, sp + 1280);
        SLICE_LOAD(h3, sp + 1536);
        SLICE_LOAD(l3, sp + 1792);
#undef SLICE_LOAD
        asm volatile("s_waitcnt vmcnt(0)" ::: "memory");
        // rule #18: fence the register-only sentinel compares BELOW the wait
        __builtin_amdgcn_sched_barrier(0);
        unsigned bad = 0u;
#define CHK(v) bad |= (unsigned)((v[0] == SENT) | (v[1] == SENT) | \
                                 (v[2] == SENT) | (v[3] == SENT))
        CHK(h0); CHK(l0); CHK(h1); CHK(l1);
        CHK(h2); CHK(l2); CHK(h3); CHK(l3);
#undef CHK
        if (!__any((int)bad)) break;
        __builtin_amdgcn_s_sleep(1);
      }
      __builtin_amdgcn_sched_barrier(0);

      // ---- scatter to swizzled LDS tiles (b128 writes) ----
      const int c0 = wave * 8 + (lane & 1);   // producer (wave*4+i) -> chunk c0+2i
      const unsigned wb = (unsigned)(beW * 256);
      *(u32x4*)&Ldh[wb + (((c0 + 0) ^ swz) << 2)] = h0;
      *(u32x4*)&Ldl[wb + (((c0 + 0) ^ swz) << 2)] = l0;
      *(u32x4*)&Ldh[wb + (((c0 + 2) ^ swz) << 2)] = h1;
      *(u32x4*)&Ldl[wb + (((c0 + 2) ^ swz) << 2)] = l1;
      *(u32x4*)&Ldh[wb + (((c0 + 4) ^ swz) << 2)] = h2;
      *(u32x4*)&Ldl[wb + (((c0 + 4) ^ swz) << 2)] = l2;
      *(u32x4*)&Ldh[wb + (((c0 + 6) ^ swz) << 2)] = h3;
      *(u32x4*)&Ldl[wb + (((c0 + 6) ^ swz) << 2)] = l3;
    }
    __syncthreads();

    // ---- MFMA: gates_tile = H[t] @ Whh_slice^T (3 independent chains) ----
    f32x4 acc;
    {
      f32x4 a0 = {0.f, 0.f, 0.f, 0.f}, a1 = a0, a2 = a0;
      if (t > 0) {
#pragma unroll
        for (int s = 0; s < 16; ++s) {
          const unsigned idx = rbase ^ (unsigned)(s << 4);
          short8 ah = __builtin_bit_cast(short8, *(const u32x4*)&Ldh[idx]);
          short8 al = __builtin_bit_cast(short8, *(const u32x4*)&Ldl[idx]);
          a0 = __builtin_amdgcn_mfma_f32_16x16x32_bf16(ah, whi[s], a0, 0, 0, 0);
          a1 = __builtin_amdgcn_mfma_f32_16x16x32_bf16(ah, wlo[s], a1, 0, 0, 0);
          a2 = __builtin_amdgcn_mfma_f32_16x16x32_bf16(al, whi[s], a2, 0, 0, 0);
        }
      }
      acc = a0 + (a1 + a2);
    }
    // D layout: row m = 16*tM + 4*(lane>>4)+r (batch), col n = 16*tN + (lane&15)
#pragma unroll
    for (int r = 0; r < 4; ++r)
      gl[tM * 16 + kb * 4 + r][tN * 16 + cc] = acc[r];
    __syncthreads();

    // ---- elementwise LSTM update: thread = (batch be, unit jo) ----
    {
      float pi = xwi + gl[be][jo];
      float pf = xwf + gl[be][16 + jo];
      float pg = xwg + gl[be][32 + jo];
      float po = xwo + gl[be][48 + jo];
      float ig = 1.f / (1.f + expf(-pi));
      float fg = 1.f / (1.f + expf(-pf));
      float gg = tanhf(pg);
      float og = 1.f / (1.f + expf(-po));
      float di = gg * ig * (1.f - ig);
      float df = c_reg * fg * (1.f - fg);     // uses c_{t-1}
      float dg = ig * (1.f - gg * gg);
      c_reg = fg * c_reg + ig * gg;
      float hn = og * tanhf(c_reg);

      // pack bf16 hi/lo pairs with neighbor lane; slice store FIRST (critical)
      unsigned hh = f2bf(hn);
      unsigned hl = f2bf(hn - bf2f(hh));
      unsigned hh_nb = (unsigned)__shfl_xor((int)hh, 1);
      unsigned hl_nb = (unsigned)__shfl_xor((int)hl, 1);
      size_t sb = ((size_t)(t + 1) * 32 + wg) * 512;
      unsigned stv; size_t sa;
      if (tid & 1) { stv = hl_nb | (hl << 16); sa = sb + 256 + (tid >> 1); }
      else         { stv = hh | (hh_nb << 16); sa = sb + (tid >> 1); }
      __hip_atomic_store(&Hp[sa], stv, __ATOMIC_RELAXED, __HIP_MEMORY_SCOPE_AGENT);

      // private stores AFTER the slice store (off the critical path)
      Hf[(size_t)(t + 1) * 16384 + (size_t)be * 512 + jh] = hn;
      size_t db = (size_t)t * 49152 + (size_t)be * 1536 + jh;
      dh[db] = di; dh[db + 512] = df; dh[db + 1024] = dg;
      fh[(size_t)t * 16384 + (size_t)be * 512 + jh] = fg;
    }
  }
}

// ---------------------------------------------------------------------------
// Suffix scan, 4-way chunked over t.
// ---------------------------------------------------------------------------
__global__ __launch_bounds__(256) void suffix_pre(
    const float* __restrict__ fh, float* __restrict__ Cp)
{
  const int g = blockIdx.x * 256 + threadIdx.x;   // 0..65535 = (k,b,jh)
  const int k = g >> 14, bjh = g & 16383;
  const int b = bjh >> 9, jh = bjh & 511;
  float P = 1.f;
  for (int t = k * 32; t < k * 32 + 32; ++t)
    P *= fh[(size_t)t * 16384 + (size_t)b * 512 + jh];
  Cp[g] = P;
}

__global__ __launch_bounds__(256) void suffix_main(
    float* __restrict__ dh, const float* __restrict__ fh,
    const float* __restrict__ Cp, float* __restrict__ Sp)
{
  const int g = blockIdx.x * 256 + threadIdx.x;   // (k,b,jh)
  const int k = g >> 14, bjh = g & 16383;
  const int b = bjh >> 9, jh = bjh & 511;
  float F = 1.f;
  for (int k2 = k + 1; k2 < 4; ++k2) F *= Cp[(k2 << 14) | bjh];
  float s0 = 0.f, s1 = 0.f, s2 = 0.f;
  for (int t = k * 32 + 31; t >= k * 32; --t) {
    size_t db = (size_t)t * 49152 + (size_t)b * 1536 + jh;
    float a0 = dh[db] * F, a1 = dh[db + 512] * F, a2 = dh[db + 1024] * F;
    dh[db] = a0; dh[db + 512] = a1; dh[db + 1024] = a2;
    s0 += a0; s1 += a1; s2 += a2;
    F *= fh[(size_t)t * 16384 + (size_t)b * 512 + jh];
  }
  size_t sb = (size_t)(k * 32 + b) * 1536 + jh;
  Sp[sb] = s0; Sp[sb + 512] = s1; Sp[sb + 1024] = s2;
}

__global__ __launch_bounds__(256) void evb_reduce(
    const float* __restrict__ Sp, float* __restrict__ evb)
{
  const int g = blockIdx.x * 256 + threadIdx.x;   // 0..49151
  evb[g] = Sp[g] + Sp[49152 + g] + Sp[98304 + g] + Sp[147456 + g];
}

// ---------------------------------------------------------------------------
// bf16 hi/lo-split MFMA GEMM (proven in R7).  128x128 tile, BK=32.
// ---------------------------------------------------------------------------
__global__ __launch_bounds__(256, 2) void gemm_bf16s(
    const float* __restrict__ A, const float* __restrict__ B,
    float* __restrict__ C, const float* __restrict__ bias,
    int M, int N, int K,
    long long sAm, long long sAk, long long aBatch,
    long long sBn, long long sBk, long long bBatch,
    long long sCm1, long long sCm2, int M1, long long cBatch)
{
  __shared__ __align__(16) unsigned Ahi[128 * 20], Alo[128 * 20];
  __shared__ __align__(16) unsigned Bhi[128 * 20], Blo[128 * 20];

  const int tid  = threadIdx.x;
  const int lane = tid & 63;
  const int wave = tid >> 6;
  const int wm   = wave >> 1;
  const int wn   = wave & 1;
  const int cc   = lane & 15;
  const int kb   = lane >> 4;
  const long long z = blockIdx.z;
  const float* Ab = A + z * aBatch;
  const float* Bb = B + z * bBatch;
  const int m0 = blockIdx.y * 128, n0 = blockIdx.x * 128;

  f32x4 acc[4][4];
#pragma unroll
  for (int i = 0; i < 4; ++i)
#pragma unroll
    for (int j = 0; j < 4; ++j) acc[i][j] = (f32x4){0.f, 0.f, 0.f, 0.f};

  for (int k0 = 0; k0 < K; k0 += 32) {
    if (sAk == 1) {
      const int r = tid >> 1, half = tid & 1;
      const float* s = Ab + (long long)(m0 + r) * sAm + (k0 + half * 16);
      f32x4 v0 = *(const f32x4*)s;
      f32x4 v1 = *(const f32x4*)(s + 4);
      f32x4 v2 = *(const f32x4*)(s + 8);
      f32x4 v3 = *(const f32x4*)(s + 12);
      u32x4 h0, h1, l0, l1;
      HiLo p;
      p = packpair(v0[0], v0[1]); h0[0] = p.hi; l0[0] = p.lo;
      p = packpair(v0[2], v0[3]); h0[1] = p.hi; l0[1] = p.lo;
      p = packpair(v1[0], v1[1]); h0[2] = p.hi; l0[2] = p.lo;
      p = packpair(v1[2], v1[3]); h0[3] = p.hi; l0[3] = p.lo;
      p = packpair(v2[0], v2[1]); h1[0] = p.hi; l1[0] = p.lo;
      p = packpair(v2[2], v2[3]); h1[1] = p.hi; l1[1] = p.lo;
      p = packpair(v3[0], v3[1]); h1[2] = p.hi; l1[2] = p.lo;
      p = packpair(v3[2], v3[3]); h1[3] = p.hi; l1[3] = p.lo;
      const int o = r * 20 + half * 8;
      *(u32x4*)&Ahi[o] = h0;  *(u32x4*)&Ahi[o + 4] = h1;
      *(u32x4*)&Alo[o] = l0;  *(u32x4*)&Alo[o + 4] = l1;
    } else {
#pragma unroll
      for (int it = 0; it < 2; ++it) {
        const int kp = tid >> 4;
        const int mr = (tid & 15) * 4 + it * 64;
        const float* s0 = Ab + (long long)(k0 + 2 * kp) * sAk + (m0 + mr);
        f32x4 va = *(const f32x4*)s0;
        f32x4 vb = *(const f32x4*)(s0 + sAk);
#pragma unroll
        for (int q = 0; q < 4; ++q) {
          HiLo p = packpair(va[q], vb[q]);
          Ahi[(mr + q) * 20 + kp] = p.hi;
          Alo[(mr + q) * 20 + kp] = p.lo;
        }
      }
    }
    if (sBk == 1) {
      const int r = tid >> 1, half = tid & 1;
      const float* s = Bb + (long long)(n0 + r) * sBn + (k0 + half * 16);
      f32x4 v0 = *(const f32x4*)s;
      f32x4 v1 = *(const f32x4*)(s + 4);
      f32x4 v2 = *(const f32x4*)(s + 8);
      f32x4 v3 = *(const f32x4*)(s + 12);
      u32x4 h0, h1, l0, l1;
      HiLo p;
      p = packpair(v0[0], v0[1]); h0[0] = p.hi; l0[0] = p.lo;
      p = packpair(v0[2], v0[3]); h0[1] = p.hi; l0[1] = p.lo;
      p = packpair(v1[0], v1[1]); h0[2] = p.hi; l0[2] = p.lo;
      p = packpair(v1[2], v1[3]); h0[3] = p.hi; l0[3] = p.lo;
      p = packpair(v2[0], v2[1]); h1[0] = p.hi; l1[0] = p.lo;
      p = packpair(v2[2], v2[3]); h1[1] = p.hi; l1[1] = p.lo;
      p = packpair(v3[0], v3[1]); h1[2] = p.hi; l1[2] = p.lo;
      p = packpair(v3[2], v3[3]); h1[3] = p.hi; l1[3] = p.lo;
      const int o = r * 20 + half * 8;
      *(u32x4*)&Bhi[o] = h0;  *(u32x4*)&Bhi[o + 4] = h1;
      *(u32x4*)&Blo[o] = l0;  *(u32x4*)&Blo[o + 4] = l1;
    } else {
#pragma unroll
      for (int it = 0; it < 2; ++it) {
        const int kp = tid >> 4;
        const int nr = (tid & 15) * 4 + it * 64;
        const float* s0 = Bb + (long long)(k0 + 2 * kp) * sBk + (n0 + nr);
        f32x4 va = *(const f32x4*)s0;
        f32x4 vb = *(const f32x4*)(s0 + sBk);
#pragma unroll
        for (int q = 0; q < 4; ++q) {
          HiLo p = packpair(va[q], vb[q]);
          Bhi[(nr + q) * 20 + kp] = p.hi;
          Blo[(nr + q) * 20 + kp] = p.lo;
        }
      }
    }
    __syncthreads();

    short8 ah[4], al[4], bh[4], bl[4];
#pragma unroll
    for (int mi = 0; mi < 4; ++mi) {
      const int row = wm * 64 + mi * 16 + cc;
      ah[mi] = __builtin_bit_cast(short8, *(const u32x4*)&Ahi[row * 20 + kb * 4]);
      al[mi] = __builtin_bit_cast(short8, *(const u32x4*)&Alo[row * 20 + kb * 4]);
    }
#pragma unroll
    for (int ni = 0; ni < 4; ++ni) {
      const int row = wn * 64 + ni * 16 + cc;
      bh[ni] = __builtin_bit_cast(short8, *(const u32x4*)&Bhi[row * 20 + kb * 4]);
      bl[ni] = __builtin_bit_cast(short8, *(const u32x4*)&Blo[row * 20 + kb * 4]);
    }
#pragma unroll
    for (int mi = 0; mi < 4; ++mi)
#pragma unroll
      for (int ni = 0; ni < 4; ++ni) {
        acc[mi][ni] = __builtin_amdgcn_mfma_f32_16x16x32_bf16(ah[mi], bh[ni], acc[mi][ni], 0, 0, 0);
        acc[mi][ni] = __builtin_amdgcn_mfma_f32_16x16x32_bf16(ah[mi], bl[ni], acc[mi][ni], 0, 0, 0);
        acc[mi][ni] = __builtin_amdgcn_mfma_f32_16x16x32_bf16(al[mi], bh[ni], acc[mi][ni], 0, 0, 0);
      }
    __syncthreads();
  }

#pragma unroll
  for (int ni = 0; ni < 4; ++ni) {
    const int ng = n0 + wn * 64 + ni * 16 + cc;
    const float bv = bias ? bias[ng] : 0.f;
#pragma unroll
    for (int mi = 0; mi < 4; ++mi) {
#pragma unroll
      for (int r = 0; r < 4; ++r) {
        const int mg = m0 + wm * 64 + mi * 16 + kb * 4 + r;
        const long long crow = z * cBatch + (long long)(mg % M1) * sCm1 +
                               (long long)(mg / M1) * sCm2;
        C[crow + ng] = acc[mi][ni][r] + bv;
      }
    }
  }
}

// ---------------------------------------------------------------------------
// Small fp32 GEMM (tiny MLP/readout layers only).
// ---------------------------------------------------------------------------
template <int BM, int BN, int TM, int TN>
__global__ __launch_bounds__(256) void gemm_f32(
    const float* __restrict__ A, const float* __restrict__ B,
    float* __restrict__ C, const float* __restrict__ bias,
    int M, int N, int K,
    long long sAm, long long sAk, long long aBatch,
    long long sBn, long long sBk, long long bBatch,
    long long sCm1, long long sCm2, int M1, long long cBatch,
    int relu)
{
  constexpr int BK = 16;
  __shared__ float As[BK][BM + 4];
  __shared__ float Bs[BK][BN + 4];
  const int tid = threadIdx.x;
  const long long z = blockIdx.z;
  const float* Ab = A + z * aBatch;
  const float* Bb = B + z * bBatch;
  const int m0 = blockIdx.y * BM, n0 = blockIdx.x * BN;
  constexpr int tn_cnt = BN / TN;
  const int tm0 = (tid / tn_cnt) * TM;
  const int tn0 = (tid % tn_cnt) * TN;

  float acc[TM][TN];
#pragma unroll
  for (int i = 0; i < TM; ++i)
#pragma unroll
    for (int j = 0; j < TN; ++j) acc[i][j] = 0.f;

  for (int k0 = 0; k0 < K; k0 += BK) {
    if (sAk == 1) {
      for (int m = tid >> 2; m < BM; m += 64) {
        const int kq = (tid & 3) * 4;
        f32x4 v = {0.f, 0.f, 0.f, 0.f};
        if (m0 + m < M) v = *(const f32x4*)(Ab + (long long)(m0 + m) * sAm + (k0 + kq));
        As[kq + 0][m] = v[0]; As[kq + 1][m] = v[1];
        As[kq + 2][m] = v[2]; As[kq + 3][m] = v[3];
      }
    } else {
      constexpr int mq_cnt = BM / 4;
      for (int kk = tid / mq_cnt; kk < BK; kk += 256 / mq_cnt) {
        const int mq = (tid % mq_cnt) * 4;
        f32x4 v = {0.f, 0.f, 0.f, 0.f};
        if (m0 + mq < M) v = *(const f32x4*)(Ab + (long long)(k0 + kk) * sAk + (m0 + mq));
        *(f32x4*)&As[kk][mq] = v;
      }
    }
    if (sBk == 1) {
      for (int n = tid >> 2; n < BN; n += 64) {
        const int kq = (tid & 3) * 4;
        f32x4 v = {0.f, 0.f, 0.f, 0.f};
        if (n0 + n < N) v = *(const f32x4*)(Bb + (long long)(n0 + n) * sBn + (k0 + kq));
        Bs[kq + 0][n] = v[0]; Bs[kq + 1][n] = v[1];
        Bs[kq + 2][n] = v[2]; Bs[kq + 3][n] = v[3];
      }
    } else {
      constexpr int nq_cnt = BN / 4;
      for (int kk = tid / nq_cnt; kk < BK; kk += 256 / nq_cnt) {
        const int nq = (tid % nq_cnt) * 4;
        f32x4 v = {0.f, 0.f, 0.f, 0.f};
        if (n0 + nq < N) v = *(const f32x4*)(Bb + (long long)(k0 + kk) * sBk + (n0 + nq));
        *(f32x4*)&Bs[kk][nq] = v;
      }
    }
    __syncthreads();

#pragma unroll
    for (int kk = 0; kk < BK; ++kk) {
      float a[TM], bb[TN];
#pragma unroll
      for (int i = 0; i < TM; ++i) a[i] = As[kk][tm0 + i];
#pragma unroll
      for (int j = 0; j < TN; ++j) bb[j] = Bs[kk][tn0 + j];
#pragma unroll
      for (int i = 0; i < TM; ++i)
#pragma unroll
        for (int j = 0; j < TN; ++j) acc[i][j] += a[i] * bb[j];
    }
    __syncthreads();
  }

#pragma unroll
  for (int i = 0; i < TM; ++i) {
    const int mg = m0 + tm0 + i;
    if (mg >= M) continue;
    const long long crow = z * cBatch + (long long)(mg % M1) * sCm1 +
                           (long long)(mg / M1) * sCm2;
#pragma unroll
    for (int j = 0; j < TN; ++j) {
      const int ng = n0 + tn0 + j;
      if (ng >= N) continue;
      float v = acc[i][j];
      if (bias) v += bias[ng];
      if (relu) v = fmaxf(v, 0.f);
      C[crow + ng] = v;
    }
  }
}

// ---------------------------------------------------------------------------
extern "C" void kernel_launch(void* const* d_in, const int* in_sizes, int n_in,
                              void* d_out, int out_size, void* d_ws, size_t ws_size,
                              hipStream_t stream) {
  const float* x   = (const float*)d_in[0];
  const float* Wih = (const float*)d_in[1];
  const float* Whh = (const float*)d_in[2];
  const float* bl  = (const float*)d_in[3];
  const float* Wd  = (const float*)d_in[4];
  const float* bd  = (const float*)d_in[5];
  const float* Ws1 = (const float*)d_in[6];
  const float* bs1 = (const float*)d_in[7];
  const float* Ws2 = (const float*)d_in[8];
  const float* bs2 = (const float*)d_in[9];
  const float* Ws3 = (const float*)d_in[10];
  const float* bs3 = (const float*)d_in[11];
  const float* Ws4 = (const float*)d_in[12];
  const float* bs4 = (const float*)d_in[13];

  float* out = (float*)d_out;
  float* ws  = (float*)d_ws;

  // d_out layout (floats)
  const long long OP = 0, OS = 320, OEX = 16704, OEH = 12599616, OEB = 37765440;

  // scratch inside ev_h output region (dead before final ev_h GEMM writes it)
  float* XW = out + OEH;                              // [128][32][2048]
  float* fh = out + OEH + 8388608;                    // [128][32][512]
  unsigned* Hp = (unsigned*)(out + OEH + 10485760);   // [129][32][512] slices
  float* Cp = out + OEH + 12599296;                   // [4][32][512]
  float* Sp = out + OEH + 12664832;                   // [4][32][1536]

  // ws scratch
  float* dh = ws;                       // [128][32][1536]  d -> A in place
  float* Hf = ws + 6291456;             // [129][32][512] fp32
  float* z1 = ws + 8404992;             // [32][512]
  float* z2 = ws + 8421376;             // [32][256]
  float* z3 = ws + 8429568;             // [32][128]

  // Hp pre-filled with the sentinel byte pattern (0x7F7F7F7F impossible as
  // packed bf16 of h in (-1,1) or its residual)
  hipMemsetAsync(Hp, 0x7F, 129ull * 32 * 512 * sizeof(unsigned), stream);
  hipMemsetAsync(Hf, 0, 16384 * sizeof(float), stream);    // H[0] = 0

  dim3 blk(256);

  // K1 (MFMA): XW[t][b][j] = x @ Wih^T + b_lstm   (M=4096, N=2048, K=256)
  gemm_bf16s<<<dim3(16, 32, 1), blk, 0, stream>>>(
      x, Wih, XW, bl, 4096, 2048, 256,
      256, 1, 0,            // A: x[m][k], k-contiguous
      256, 1, 0,            // B: Wih[n][k], k-contiguous
      65536, 2048, 128, 0); // C: XW[t=m%128][b=m/128][n]

  // K2: persistent recurrence (32 WGs x 512 threads, sentinel dataflow)
  lstm_rec<<<dim3(32), dim3(512), 0, stream>>>(Whh, XW, Hp, Hf, dh, fh);

  // K3: chunked suffix products, A in place, ev_b
  suffix_pre<<<dim3(256), blk, 0, stream>>>(fh, Cp);
  suffix_main<<<dim3(256), blk, 0, stream>>>(dh, fh, Cp, Sp);
  evb_reduce<<<dim3(192), blk, 0, stream>>>(Sp, out + OEB);

  // MLP + readout on last = Hf[128] (tiny, fp32)
  const float* hlast = Hf + 2097152;
  gemm_f32<32, 32, 2, 2><<<dim3(16, 1, 1), blk, 0, stream>>>(
      hlast, Ws1, z1, bs1, 32, 512, 512, 512, 1, 0, 512, 1, 0, 512, 0, 32, 0, 1);
  gemm_f32<32, 32, 2, 2><<<dim3(8, 1, 1), blk, 0, stream>>>(
      z1, Ws2, z2, bs2, 32, 256, 512, 512, 1, 0, 512, 1, 0, 256, 0, 32, 0, 1);
  gemm_f32<32, 32, 2, 2><<<dim3(4, 1, 1), blk, 0, stream>>>(
      z2, Ws3, z3, bs3, 32, 128, 256, 256, 1, 0, 256, 1, 0, 128, 0, 32, 0, 1);
  gemm_f32<32, 32, 2, 2><<<dim3(16, 1, 1), blk, 0, stream>>>(
      z3, Ws4, out + OS, bs4, 32, 512, 128, 128, 1, 0, 128, 1, 0, 512, 0, 32, 0, 0);
  gemm_f32<32, 32, 2, 2><<<dim3(1, 1, 1), blk, 0, stream>>>(
      hlast, Wd, out + OP, bd, 32, 10, 512, 512, 1, 0, 512, 1, 0, 10, 0, 32, 0, 0);

  // K4 (MFMA): ev_x[b][j][i] = sum_t A[t][b][j] * x[b][t][i]
  gemm_bf16s<<<dim3(2, 12, 32), blk, 0, stream>>>(
      dh, x, out + OEX, nullptr, 1536, 256, 128,
      1, 49152, 1536,       // A: dh[t][b][j], m=j contiguous
      1, 256, 32768,        // B: x[b][t][i], n=i contiguous
      256, 0, 1536, 393216);

  // K5 (MFMA): ev_h[b][j][k] = sum_t A[t][b][j] * h_{t-1}[b][k]
  // (runs last: overwrites XW/fh/Hp/Cp/Sp scratch living in the ev_h region)
  gemm_bf16s<<<dim3(4, 12, 32), blk, 0, stream>>>(
      dh, Hf, out + OEH, nullptr, 1536, 512, 128,
      1, 49152, 1536,       // A: dh[t][b][j]
      1, 16384, 512,        // B: Hf[t][b][k], n=k contiguous
      512, 0, 1536, 786432);
}

// Round 10
// 633.587 us; speedup vs baseline: 4.3568x; 1.2223x over previous
//
#include <hip/hip_runtime.h>

// ---------------------------------------------------------------------------
// EPROP3_LSTM: e-prop LSTM fwd.  Reformulation:
//   ev_x[b,j,k] = sum_t A_t[b,j] * x_t[b,k],   A_t = d_t * F_t, F_t = prod_{s>t} f_s
//   ev_h[b,j,k] = sum_t A_t[b,j] * h_{t-1}[b,k]
//   ev_b[b,j]   = sum_t A_t[b,j]
// => sequential LSTM recurrence + suffix scan + batched GEMMs (K=T=128).
//
// Round-10: R9 sentinel dataflow, but the h-exchange carries bf16 HI only
// (1KB/slice).  The W_lo term (h_hi@W_lo) is kept locally in registers;
// only the h_lo@W_hi term (~3e-4 rms per gate) is dropped.  Halves poll
// traffic, slice loads, LDS scatter, and MFMA count per step.
// K1/K4/K5 on matrix cores via bf16 hi/lo 3-term split (proven in R7).
// ---------------------------------------------------------------------------

typedef __attribute__((ext_vector_type(8))) short short8;
typedef __attribute__((ext_vector_type(4))) float f32x4;
typedef __attribute__((ext_vector_type(4))) unsigned u32x4;

#define DEV static __device__ __forceinline__

DEV unsigned f2bf(float x) {
  union { float f; unsigned u; } v; v.f = x;
  return (v.u + 0x7fffu + ((v.u >> 16) & 1u)) >> 16;
}
DEV float bf2f(unsigned b) {
  union { float f; unsigned u; } v; v.u = b << 16;
  return v.f;
}
struct HiLo { unsigned hi, lo; };
// pack two floats into (hi-bf16 pair, lo-bf16 pair)
DEV HiLo packpair(float a, float b) {
  unsigned ha = f2bf(a), hb = f2bf(b);
  unsigned la = f2bf(a - bf2f(ha)), lb = f2bf(b - bf2f(hb));
  HiLo r; r.hi = ha | (hb << 16); r.lo = la | (lb << 16);
  return r;
}

#define SENT 0x7F7F7F7Fu

// ---------------------------------------------------------------------------
// Persistent LSTM recurrence.  32 WGs x 512 threads.  WG wg owns hidden units
// [wg*16, wg*16+16) -> 64 gate rows.  Whh slice in registers as bf16 hi/lo
// MFMA B-fragments.  Sentinel dataflow sync; hi-only h exchange.
// ---------------------------------------------------------------------------
__global__ __launch_bounds__(512, 1) void lstm_rec(
    const float* __restrict__ Whh,        // [2048][512]
    const float* __restrict__ XW,         // [128][32][2048]  x@Wih^T + b
    unsigned* __restrict__ Hp,            // [129][32][256] hi slices, SENT-filled
    float* __restrict__ Hf,               // [129][32][512] fp32 (private)
    float* __restrict__ dh,               // [128][32][1536] (private)
    float* __restrict__ fh)               // [128][32][512] (private)
{
  const int wg   = blockIdx.x;            // 0..31
  const int tid  = threadIdx.x;           // 0..511
  const int lane = tid & 63;
  const int wave = tid >> 6;              // 0..7
  const int tM   = wave & 1;              // batch-tile (0..1)
  const int tN   = wave >> 1;             // row-tile   (0..3)

  __shared__ __align__(16) unsigned Ldh[32 * 256];  // hi bf16 pairs [be][kp]
  __shared__ float gl[32][68];                      // gates tile [b][r]

  const int cc = lane & 15;
  const int kb = lane >> 4;

  // ---- load Whh B-fragments once (hi/lo bf16 split) ----
  const int rloc  = tN * 16 + cc;                              // local row 0..63
  const int jglob = (rloc >> 4) * 512 + wg * 16 + (rloc & 15); // global gate row
  short8 whi[16], wlo[16];
#pragma unroll
  for (int s = 0; s < 16; ++s) {
    const float* wp = Whh + (size_t)jglob * 512 + s * 32 + kb * 8;
    f32x4 w0 = *(const f32x4*)wp;
    f32x4 w1 = *(const f32x4*)(wp + 4);
    short8 hi, lo;
#pragma unroll
    for (int j = 0; j < 4; ++j) {
      unsigned h0 = f2bf(w0[j]);
      hi[j] = (short)h0;  lo[j] = (short)f2bf(w0[j] - bf2f(h0));
      unsigned h1 = f2bf(w1[j]);
      hi[4 + j] = (short)h1;  lo[4 + j] = (short)f2bf(w1[j] - bf2f(h1));
    }
    whi[s] = hi; wlo[s] = lo;
  }

  // MFMA A-fragment LDS read base (dword index), XOR-swizzled
  const int bA = tM * 16 + cc;
  const int mz = bA & 7;
  const unsigned rbase = (unsigned)(bA * 256 + ((kb ^ (mz & 3)) << 2) + ((mz >> 2) << 4));

  // staging write mapping (per lane): row beW, chunk c ^ (beW&7)
  const int beW = lane >> 1;
  const int swz = beW & 7;

  const int be = tid >> 4;          // elementwise: batch 0..31
  const int jo = tid & 15;          // elementwise: local hidden unit 0..15
  const int jh = wg * 16 + jo;      // global hidden unit
  float c_reg = 0.f;

  for (int t = 0; t < 128; ++t) {
    // ---- XW prefetch (plain loads; complete under the poll) ----
    const float* xwp = XW + (size_t)t * 65536 + (size_t)be * 2048 + wg * 16 + jo;
    float xwi = xwp[0], xwf = xwp[512], xwg = xwp[1024], xwo = xwp[1536];

    if (t > 0) {
      // ---- poll the DATA of this wave's 4 producers until sentinel-free ----
      const unsigned* sp = Hp + ((size_t)t * 32 + wave * 4) * 256 + lane * 4;
      u32x4 h0, h1, h2, h3;
      for (;;) {
#define SLICE_LOAD(dst, addr)                                          \
        asm volatile("global_load_dwordx4 %0, %1, off sc0 sc1"         \
                     : "=&v"(dst) : "v"(addr) : "memory")
        SLICE_LOAD(h0, sp);
        SLICE_LOAD(h1, sp + 256);
        SLICE_LOAD(h2, sp + 512);
        SLICE_LOAD(h3, sp + 768);
#undef SLICE_LOAD
        asm volatile("s_waitcnt vmcnt(0)" ::: "memory");
        // rule #18: fence the register-only sentinel compares BELOW the wait
        __builtin_amdgcn_sched_barrier(0);
        unsigned bad = 0u;
#define CHK(v) bad |= (unsigned)((v[0] == SENT) | (v[1] == SENT) | \
                                 (v[2] == SENT) | (v[3] == SENT))
        CHK(h0); CHK(h1); CHK(h2); CHK(h3);
#undef CHK
        if (!__any((int)bad)) break;
        __builtin_amdgcn_s_sleep(1);
      }
      __builtin_amdgcn_sched_barrier(0);

      // ---- scatter to swizzled LDS tile (b128 writes) ----
      const int c0 = wave * 8 + (lane & 1);   // producer (wave*4+i) -> chunk c0+2i
      const unsigned wb = (unsigned)(beW * 256);
      *(u32x4*)&Ldh[wb + (((c0 + 0) ^ swz) << 2)] = h0;
      *(u32x4*)&Ldh[wb + (((c0 + 2) ^ swz) << 2)] = h1;
      *(u32x4*)&Ldh[wb + (((c0 + 4) ^ swz) << 2)] = h2;
      *(u32x4*)&Ldh[wb + (((c0 + 6) ^ swz) << 2)] = h3;
    }
    __syncthreads();

    // ---- MFMA: gates_tile = H[t] @ Whh_slice^T (2 independent chains) ----
    f32x4 acc;
    {
      f32x4 a0 = {0.f, 0.f, 0.f, 0.f}, a1 = a0;
      if (t > 0) {
#pragma unroll
        for (int s = 0; s < 16; ++s) {
          const unsigned idx = rbase ^ (unsigned)(s << 4);
          short8 ah = __builtin_bit_cast(short8, *(const u32x4*)&Ldh[idx]);
          a0 = __builtin_amdgcn_mfma_f32_16x16x32_bf16(ah, whi[s], a0, 0, 0, 0);
          a1 = __builtin_amdgcn_mfma_f32_16x16x32_bf16(ah, wlo[s], a1, 0, 0, 0);
        }
      }
      acc = a0 + a1;
    }
    // D layout: row m = 16*tM + 4*(lane>>4)+r (batch), col n = 16*tN + (lane&15)
#pragma unroll
    for (int r = 0; r < 4; ++r)
      gl[tM * 16 + kb * 4 + r][tN * 16 + cc] = acc[r];
    __syncthreads();

    // ---- elementwise LSTM update: thread = (batch be, unit jo) ----
    {
      float pi = xwi + gl[be][jo];
      float pf = xwf + gl[be][16 + jo];
      float pg = xwg + gl[be][32 + jo];
      float po = xwo + gl[be][48 + jo];
      float ig = 1.f / (1.f + expf(-pi));
      float fg = 1.f / (1.f + expf(-pf));
      float gg = tanhf(pg);
      float og = 1.f / (1.f + expf(-po));
      float di = gg * ig * (1.f - ig);
      float df = c_reg * fg * (1.f - fg);     // uses c_{t-1}
      float dg = ig * (1.f - gg * gg);
      c_reg = fg * c_reg + ig * gg;
      float hn = og * tanhf(c_reg);

      // pack bf16 hi pair with neighbor lane; slice store FIRST (critical)
      unsigned hh = f2bf(hn);
      unsigned hh_nb = (unsigned)__shfl_xor((int)hh, 1);
      if (!(tid & 1)) {
        unsigned stv = hh | (hh_nb << 16);
        size_t sa = ((size_t)(t + 1) * 32 + wg) * 256 + (tid >> 1);
        __hip_atomic_store(&Hp[sa], stv, __ATOMIC_RELAXED, __HIP_MEMORY_SCOPE_AGENT);
      }

      // private stores AFTER the slice store (off the critical path)
      Hf[(size_t)(t + 1) * 16384 + (size_t)be * 512 + jh] = hn;
      size_t db = (size_t)t * 49152 + (size_t)be * 1536 + jh;
      dh[db] = di; dh[db + 512] = df; dh[db + 1024] = dg;
      fh[(size_t)t * 16384 + (size_t)be * 512 + jh] = fg;
    }
  }
}

// ---------------------------------------------------------------------------
// Suffix scan, 4-way chunked over t.
// ---------------------------------------------------------------------------
__global__ __launch_bounds__(256) void suffix_pre(
    const float* __restrict__ fh, float* __restrict__ Cp)
{
  const int g = blockIdx.x * 256 + threadIdx.x;   // 0..65535 = (k,b,jh)
  const int k = g >> 14, bjh = g & 16383;
  const int b = bjh >> 9, jh = bjh & 511;
  float P = 1.f;
  for (int t = k * 32; t < k * 32 + 32; ++t)
    P *= fh[(size_t)t * 16384 + (size_t)b * 512 + jh];
  Cp[g] = P;
}

__global__ __launch_bounds__(256) void suffix_main(
    float* __restrict__ dh, const float* __restrict__ fh,
    const float* __restrict__ Cp, float* __restrict__ Sp)
{
  const int g = blockIdx.x * 256 + threadIdx.x;   // (k,b,jh)
  const int k = g >> 14, bjh = g & 16383;
  const int b = bjh >> 9, jh = bjh & 511;
  float F = 1.f;
  for (int k2 = k + 1; k2 < 4; ++k2) F *= Cp[(k2 << 14) | bjh];
  float s0 = 0.f, s1 = 0.f, s2 = 0.f;
  for (int t = k * 32 + 31; t >= k * 32; --t) {
    size_t db = (size_t)t * 49152 + (size_t)b * 1536 + jh;
    float a0 = dh[db] * F, a1 = dh[db + 512] * F, a2 = dh[db + 1024] * F;
    dh[db] = a0; dh[db + 512] = a1; dh[db + 1024] = a2;
    s0 += a0; s1 += a1; s2 += a2;
    F *= fh[(size_t)t * 16384 + (size_t)b * 512 + jh];
  }
  size_t sb = (size_t)(k * 32 + b) * 1536 + jh;
  Sp[sb] = s0; Sp[sb + 512] = s1; Sp[sb + 1024] = s2;
}

__global__ __launch_bounds__(256) void evb_reduce(
    const float* __restrict__ Sp, float* __restrict__ evb)
{
  const int g = blockIdx.x * 256 + threadIdx.x;   // 0..49151
  evb[g] = Sp[g] + Sp[49152 + g] + Sp[98304 + g] + Sp[147456 + g];
}

// ---------------------------------------------------------------------------
// bf16 hi/lo-split MFMA GEMM (proven in R7).  128x128 tile, BK=32.
// ---------------------------------------------------------------------------
__global__ __launch_bounds__(256, 2) void gemm_bf16s(
    const float* __restrict__ A, const float* __restrict__ B,
    float* __restrict__ C, const float* __restrict__ bias,
    int M, int N, int K,
    long long sAm, long long sAk, long long aBatch,
    long long sBn, long long sBk, long long bBatch,
    long long sCm1, long long sCm2, int M1, long long cBatch)
{
  __shared__ __align__(16) unsigned Ahi[128 * 20], Alo[128 * 20];
  __shared__ __align__(16) unsigned Bhi[128 * 20], Blo[128 * 20];

  const int tid  = threadIdx.x;
  const int lane = tid & 63;
  const int wave = tid >> 6;
  const int wm   = wave >> 1;
  const int wn   = wave & 1;
  const int cc   = lane & 15;
  const int kb   = lane >> 4;
  const long long z = blockIdx.z;
  const float* Ab = A + z * aBatch;
  const float* Bb = B + z * bBatch;
  const int m0 = blockIdx.y * 128, n0 = blockIdx.x * 128;

  f32x4 acc[4][4];
#pragma unroll
  for (int i = 0; i < 4; ++i)
#pragma unroll
    for (int j = 0; j < 4; ++j) acc[i][j] = (f32x4){0.f, 0.f, 0.f, 0.f};

  for (int k0 = 0; k0 < K; k0 += 32) {
    if (sAk == 1) {
      const int r = tid >> 1, half = tid & 1;
      const float* s = Ab + (long long)(m0 + r) * sAm + (k0 + half * 16);
      f32x4 v0 = *(const f32x4*)s;
      f32x4 v1 = *(const f32x4*)(s + 4);
      f32x4 v2 = *(const f32x4*)(s + 8);
      f32x4 v3 = *(const f32x4*)(s + 12);
      u32x4 h0, h1, l0, l1;
      HiLo p;
      p = packpair(v0[0], v0[1]); h0[0] = p.hi; l0[0] = p.lo;
      p = packpair(v0[2], v0[3]); h0[1] = p.hi; l0[1] = p.lo;
      p = packpair(v1[0], v1[1]); h0[2] = p.hi; l0[2] = p.lo;
      p = packpair(v1[2], v1[3]); h0[3] = p.hi; l0[3] = p.lo;
      p = packpair(v2[0], v2[1]); h1[0] = p.hi; l1[0] = p.lo;
      p = packpair(v2[2], v2[3]); h1[1] = p.hi; l1[1] = p.lo;
      p = packpair(v3[0], v3[1]); h1[2] = p.hi; l1[2] = p.lo;
      p = packpair(v3[2], v3[3]); h1[3] = p.hi; l1[3] = p.lo;
      const int o = r * 20 + half * 8;
      *(u32x4*)&Ahi[o] = h0;  *(u32x4*)&Ahi[o + 4] = h1;
      *(u32x4*)&Alo[o] = l0;  *(u32x4*)&Alo[o + 4] = l1;
    } else {
#pragma unroll
      for (int it = 0; it < 2; ++it) {
        const int kp = tid >> 4;
        const int mr = (tid & 15) * 4 + it * 64;
        const float* s0 = Ab + (long long)(k0 + 2 * kp) * sAk + (m0 + mr);
        f32x4 va = *(const f32x4*)s0;
        f32x4 vb = *(const f32x4*)(s0 + sAk);
#pragma unroll
        for (int q = 0; q < 4; ++q) {
          HiLo p = packpair(va[q], vb[q]);
          Ahi[(mr + q) * 20 + kp] = p.hi;
          Alo[(mr + q) * 20 + kp] = p.lo;
        }
      }
    }
    if (sBk == 1) {
      const int r = tid >> 1, half = tid & 1;
      const float* s = Bb + (long long)(n0 + r) * sBn + (k0 + half * 16);
      f32x4 v0 = *(const f32x4*)s;
      f32x4 v1 = *(const f32x4*)(s + 4);
      f32x4 v2 = *(const f32x4*)(s + 8);
      f32x4 v3 = *(const f32x4*)(s + 12);
      u32x4 h0, h1, l0, l1;
      HiLo p;
      p = packpair(v0[0], v0[1]); h0[0] = p.hi; l0[0] = p.lo;
      p = packpair(v0[2], v0[3]); h0[1] = p.hi; l0[1] = p.lo;
      p = packpair(v1[0], v1[1]); h0[2] = p.hi; l0[2] = p.lo;
      p = packpair(v1[2], v1[3]); h0[3] = p.hi; l0[3] = p.lo;
      p = packpair(v2[0], v2[1]); h1[0] = p.hi; l1[0] = p.lo;
      p = packpair(v2[2], v2[3]); h1[1] = p.hi; l1[1] = p.lo;
      p = packpair(v3[0], v3[1]); h1[2] = p.hi; l1[2] = p.lo;
      p = packpair(v3[2], v3[3]); h1[3] = p.hi; l1[3] = p.lo;
      const int o = r * 20 + half * 8;
      *(u32x4*)&Bhi[o] = h0;  *(u32x4*)&Bhi[o + 4] = h1;
      *(u32x4*)&Blo[o] = l0;  *(u32x4*)&Blo[o + 4] = l1;
    } else {
#pragma unroll
      for (int it = 0; it < 2; ++it) {
        const int kp = tid >> 4;
        const int nr = (tid & 15) * 4 + it * 64;
        const float* s0 = Bb + (long long)(k0 + 2 * kp) * sBk + (n0 + nr);
        f32x4 va = *(const f32x4*)s0;
        f32x4 vb = *(const f32x4*)(s0 + sBk);
#pragma unroll
        for (int q = 0; q < 4; ++q) {
          HiLo p = packpair(va[q], vb[q]);
          Bhi[(nr + q) * 20 + kp] = p.hi;
          Blo[(nr + q) * 20 + kp] = p.lo;
        }
      }
    }
    __syncthreads();

    short8 ah[4], al[4], bh[4], bl[4];
#pragma unroll
    for (int mi = 0; mi < 4; ++mi) {
      const int row = wm * 64 + mi * 16 + cc;
      ah[mi] = __builtin_bit_cast(short8, *(const u32x4*)&Ahi[row * 20 + kb * 4]);
      al[mi] = __builtin_bit_cast(short8, *(const u32x4*)&Alo[row * 20 + kb * 4]);
    }
#pragma unroll
    for (int ni = 0; ni < 4; ++ni) {
      const int row = wn * 64 + ni * 16 + cc;
      bh[ni] = __builtin_bit_cast(short8, *(const u32x4*)&Bhi[row * 20 + kb * 4]);
      bl[ni] = __builtin_bit_cast(short8, *(const u32x4*)&Blo[row * 20 + kb * 4]);
    }
#pragma unroll
    for (int mi = 0; mi < 4; ++mi)
#pragma unroll
      for (int ni = 0; ni < 4; ++ni) {
        acc[mi][ni] = __builtin_amdgcn_mfma_f32_16x16x32_bf16(ah[mi], bh[ni], acc[mi][ni], 0, 0, 0);
        acc[mi][ni] = __builtin_amdgcn_mfma_f32_16x16x32_bf16(ah[mi], bl[ni], acc[mi][ni], 0, 0, 0);
        acc[mi][ni] = __builtin_amdgcn_mfma_f32_16x16x32_bf16(al[mi], bh[ni], acc[mi][ni], 0, 0, 0);
      }
    __syncthreads();
  }

#pragma unroll
  for (int ni = 0; ni < 4; ++ni) {
    const int ng = n0 + wn * 64 + ni * 16 + cc;
    const float bv = bias ? bias[ng] : 0.f;
#pragma unroll
    for (int mi = 0; mi < 4; ++mi) {
#pragma unroll
      for (int r = 0; r < 4; ++r) {
        const int mg = m0 + wm * 64 + mi * 16 + kb * 4 + r;
        const long long crow = z * cBatch + (long long)(mg % M1) * sCm1 +
                               (long long)(mg / M1) * sCm2;
        C[crow + ng] = acc[mi][ni][r] + bv;
      }
    }
  }
}

// ---------------------------------------------------------------------------
// Small fp32 GEMM (tiny MLP/readout layers only).
// ---------------------------------------------------------------------------
template <int BM, int BN, int TM, int TN>
__global__ __launch_bounds__(256) void gemm_f32(
    const float* __restrict__ A, const float* __restrict__ B,
    float* __restrict__ C, const float* __restrict__ bias,
    int M, int N, int K,
    long long sAm, long long sAk, long long aBatch,
    long long sBn, long long sBk, long long bBatch,
    long long sCm1, long long sCm2, int M1, long long cBatch,
    int relu)
{
  constexpr int BK = 16;
  __shared__ float As[BK][BM + 4];
  __shared__ float Bs[BK][BN + 4];
  const int tid = threadIdx.x;
  const long long z = blockIdx.z;
  const float* Ab = A + z * aBatch;
  const float* Bb = B + z * bBatch;
  const int m0 = blockIdx.y * BM, n0 = blockIdx.x * BN;
  constexpr int tn_cnt = BN / TN;
  const int tm0 = (tid / tn_cnt) * TM;
  const int tn0 = (tid % tn_cnt) * TN;

  float acc[TM][TN];
#pragma unroll
  for (int i = 0; i < TM; ++i)
#pragma unroll
    for (int j = 0; j < TN; ++j) acc[i][j] = 0.f;

  for (int k0 = 0; k0 < K; k0 += BK) {
    if (sAk == 1) {
      for (int m = tid >> 2; m < BM; m += 64) {
        const int kq = (tid & 3) * 4;
        f32x4 v = {0.f, 0.f, 0.f, 0.f};
        if (m0 + m < M) v = *(const f32x4*)(Ab + (long long)(m0 + m) * sAm + (k0 + kq));
        As[kq + 0][m] = v[0]; As[kq + 1][m] = v[1];
        As[kq + 2][m] = v[2]; As[kq + 3][m] = v[3];
      }
    } else {
      constexpr int mq_cnt = BM / 4;
      for (int kk = tid / mq_cnt; kk < BK; kk += 256 / mq_cnt) {
        const int mq = (tid % mq_cnt) * 4;
        f32x4 v = {0.f, 0.f, 0.f, 0.f};
        if (m0 + mq < M) v = *(const f32x4*)(Ab + (long long)(k0 + kk) * sAk + (m0 + mq));
        *(f32x4*)&As[kk][mq] = v;
      }
    }
    if (sBk == 1) {
      for (int n = tid >> 2; n < BN; n += 64) {
        const int kq = (tid & 3) * 4;
        f32x4 v = {0.f, 0.f, 0.f, 0.f};
        if (n0 + n < N) v = *(const f32x4*)(Bb + (long long)(n0 + n) * sBn + (k0 + kq));
        Bs[kq + 0][n] = v[0]; Bs[kq + 1][n] = v[1];
        Bs[kq + 2][n] = v[2]; Bs[kq + 3][n] = v[3];
      }
    } else {
      constexpr int nq_cnt = BN / 4;
      for (int kk = tid / nq_cnt; kk < BK; kk += 256 / nq_cnt) {
        const int nq = (tid % nq_cnt) * 4;
        f32x4 v = {0.f, 0.f, 0.f, 0.f};
        if (n0 + nq < N) v = *(const f32x4*)(Bb + (long long)(k0 + kk) * sBk + (n0 + nq));
        *(f32x4*)&Bs[kk][nq] = v;
      }
    }
    __syncthreads();

#pragma unroll
    for (int kk = 0; kk < BK; ++kk) {
      float a[TM], bb[TN];
#pragma unroll
      for (int i = 0; i < TM; ++i) a[i] = As[kk][tm0 + i];
#pragma unroll
      for (int j = 0; j < TN; ++j) bb[j] = Bs[kk][tn0 + j];
#pragma unroll
      for (int i = 0; i < TM; ++i)
#pragma unroll
        for (int j = 0; j < TN; ++j) acc[i][j] += a[i] * bb[j];
    }
    __syncthreads();
  }

#pragma unroll
  for (int i = 0; i < TM; ++i) {
    const int mg = m0 + tm0 + i;
    if (mg >= M) continue;
    const long long crow = z * cBatch + (long long)(mg % M1) * sCm1 +
                           (long long)(mg / M1) * sCm2;
#pragma unroll
    for (int j = 0; j < TN; ++j) {
      const int ng = n0 + tn0 + j;
      if (ng >= N) continue;
      float v = acc[i][j];
      if (bias) v += bias[ng];
      if (relu) v = fmaxf(v, 0.f);
      C[crow + ng] = v;
    }
  }
}

// ---------------------------------------------------------------------------
extern "C" void kernel_launch(void* const* d_in, const int* in_sizes, int n_in,
                              void* d_out, int out_size, void* d_ws, size_t ws_size,
                              hipStream_t stream) {
  const float* x   = (const float*)d_in[0];
  const float* Wih = (const float*)d_in[1];
  const float* Whh = (const float*)d_in[2];
  const float* bl  = (const float*)d_in[3];
  const float* Wd  = (const float*)d_in[4];
  const float* bd  = (const float*)d_in[5];
  const float* Ws1 = (const float*)d_in[6];
  const float* bs1 = (const float*)d_in[7];
  const float* Ws2 = (const float*)d_in[8];
  const float* bs2 = (const float*)d_in[9];
  const float* Ws3 = (const float*)d_in[10];
  const float* bs3 = (const float*)d_in[11];
  const float* Ws4 = (const float*)d_in[12];
  const float* bs4 = (const float*)d_in[13];

  float* out = (float*)d_out;
  float* ws  = (float*)d_ws;

  // d_out layout (floats)
  const long long OP = 0, OS = 320, OEX = 16704, OEH = 12599616, OEB = 37765440;

  // scratch inside ev_h output region (dead before final ev_h GEMM writes it)
  float* XW = out + OEH;                              // [128][32][2048]
  float* fh = out + OEH + 8388608;                    // [128][32][512]
  unsigned* Hp = (unsigned*)(out + OEH + 10485760);   // [129][32][256] hi slices
  float* Cp = out + OEH + 12599296;                   // [4][32][512]
  float* Sp = out + OEH + 12664832;                   // [4][32][1536]

  // ws scratch
  float* dh = ws;                       // [128][32][1536]  d -> A in place
  float* Hf = ws + 6291456;             // [129][32][512] fp32
  float* z1 = ws + 8404992;             // [32][512]
  float* z2 = ws + 8421376;             // [32][256]
  float* z3 = ws + 8429568;             // [32][128]

  // Hp pre-filled with the sentinel byte pattern (0x7F7F7F7F impossible as
  // packed bf16 of h in (-1,1))
  hipMemsetAsync(Hp, 0x7F, 129ull * 32 * 256 * sizeof(unsigned), stream);
  hipMemsetAsync(Hf, 0, 16384 * sizeof(float), stream);    // H[0] = 0

  dim3 blk(256);

  // K1 (MFMA): XW[t][b][j] = x @ Wih^T + b_lstm   (M=4096, N=2048, K=256)
  gemm_bf16s<<<dim3(16, 32, 1), blk, 0, stream>>>(
      x, Wih, XW, bl, 4096, 2048, 256,
      256, 1, 0,            // A: x[m][k], k-contiguous
      256, 1, 0,            // B: Wih[n][k], k-contiguous
      65536, 2048, 128, 0); // C: XW[t=m%128][b=m/128][n]

  // K2: persistent recurrence (32 WGs x 512 threads, sentinel dataflow)
  lstm_rec<<<dim3(32), dim3(512), 0, stream>>>(Whh, XW, Hp, Hf, dh, fh);

  // K3: chunked suffix products, A in place, ev_b
  suffix_pre<<<dim3(256), blk, 0, stream>>>(fh, Cp);
  suffix_main<<<dim3(256), blk, 0, stream>>>(dh, fh, Cp, Sp);
  evb_reduce<<<dim3(192), blk, 0, stream>>>(Sp, out + OEB);

  // MLP + readout on last = Hf[128] (tiny, fp32)
  const float* hlast = Hf + 2097152;
  gemm_f32<32, 32, 2, 2><<<dim3(16, 1, 1), blk, 0, stream>>>(
      hlast, Ws1, z1, bs1, 32, 512, 512, 512, 1, 0, 512, 1, 0, 512, 0, 32, 0, 1);
  gemm_f32<32, 32, 2, 2><<<dim3(8, 1, 1), blk, 0, stream>>>(
      z1, Ws2, z2, bs2, 32, 256, 512, 512, 1, 0, 512, 1, 0, 256, 0, 32, 0, 1);
  gemm_f32<32, 32, 2, 2><<<dim3(4, 1, 1), blk, 0, stream>>>(
      z2, Ws3, z3, bs3, 32, 128, 256, 256, 1, 0, 256, 1, 0, 128, 0, 32, 0, 1);
  gemm_f32<32, 32, 2, 2><<<dim3(16, 1, 1), blk, 0, stream>>>(
      z3, Ws4, out + OS, bs4, 32, 512, 128, 128, 1, 0, 128, 1, 0, 512, 0, 32, 0, 0);
  gemm_f32<32, 32, 2, 2><<<dim3(1, 1, 1), blk, 0, stream>>>(
      hlast, Wd, out + OP, bd, 32, 10, 512, 512, 1, 0, 512, 1, 0, 10, 0, 32, 0, 0);

  // K4 (MFMA): ev_x[b][j][i] = sum_t A[t][b][j] * x[b][t][i]
  gemm_bf16s<<<dim3(2, 12, 32), blk, 0, stream>>>(
      dh, x, out + OEX, nullptr, 1536, 256, 128,
      1, 49152, 1536,       // A: dh[t][b][j], m=j contiguous
      1, 256, 32768,        // B: x[b][t][i], n=i contiguous
      256, 0, 1536, 393216);

  // K5 (MFMA): ev_h[b][j][k] = sum_t A[t][b][j] * h_{t-1}[b][k]
  // (runs last: overwrites XW/fh/Hp/Cp/Sp scratch living in the ev_h region)
  gemm_bf16s<<<dim3(4, 12, 32), blk, 0, stream>>>(
      dh, Hf, out + OEH, nullptr, 1536, 512, 128,
      1, 49152, 1536,       // A: dh[t][b][j]
      1, 16384, 512,        // B: Hf[t][b][k], n=k contiguous
      512, 0, 1536, 786432);
}